// Round 3
// baseline (3296.142 us; speedup 1.0000x reference)
//
#include <hip/hip_runtime.h>
#include <hip/hip_bf16.h>

// ---------------- common helpers ----------------
typedef unsigned short u16;

__device__ __forceinline__ float bf2f(u16 u) {
    return __uint_as_float(((unsigned int)u) << 16);
}
__device__ __forceinline__ u16 f2bf(float f) {
    unsigned int x = __float_as_uint(f);
    unsigned int r = x + 0x7fffu + ((x >> 16) & 1u);
    return (u16)(r >> 16);
}

#define WIMG 128
#define HIMG 128
#define BIMG 8
#define CIN  64
#define NPOINT 128
#define NINST 512

// ---------------- prep kernels ----------------
// w1: (256 oc, 64 ic, 3, 3) f32 -> wT: (576 k, 256 oc) f32
__global__ __launch_bounds__(256) void k_transpose_w1(const float* __restrict__ w,
                                                      float* __restrict__ wT) {
    int idx = blockIdx.x * 256 + threadIdx.x;   // 147456 total
    int oc = idx / 576, k = idx % 576;
    wT[k * 256 + oc] = w[idx];
}

// w2: (254 oc, 256 ic) f32 -> wT2: (256 ic, 256 oc) f32, zero-padded oc>=254
__global__ __launch_bounds__(256) void k_transpose_w2(const float* __restrict__ w,
                                                      float* __restrict__ wT) {
    int idx = blockIdx.x * 256 + threadIdx.x;   // 65536 total
    int ic = idx >> 8, oc = idx & 255;
    wT[idx] = (oc < 254) ? w[oc * 256 + ic] : 0.f;
}

// W2 = wo @ whead (256x2), b2 = bo @ whead + bhead (2), all f32
__global__ __launch_bounds__(256) void k_headfuse(const float* __restrict__ wo,
                                                  const float* __restrict__ bo,
                                                  const float* __restrict__ whead,
                                                  const float* __restrict__ bhead,
                                                  float* __restrict__ W2,
                                                  float* __restrict__ b2) {
    int idx = blockIdx.x * 256 + threadIdx.x;   // 512 total
    if (idx < 512) {
        int c = idx >> 1, j = idx & 1;
        float s = 0.f;
        for (int t = 0; t < 256; ++t)
            s = fmaf(wo[c * 256 + t], whead[t * 2 + j], s);
        W2[idx] = s;
    }
    if (idx < 2) {
        float s = bhead[idx];
        for (int t = 0; t < 256; ++t)
            s = fmaf(bo[t], whead[t * 2 + idx], s);
        b2[idx] = s;
    }
}

// ---------------- init polys ----------------
// out0 = init_polys*4 (f32); points1 = [ct, init_polys] fp32 (512,129,2)
__global__ __launch_bounds__(256) void k_init(const float* __restrict__ whp,
                                              const int* __restrict__ ct_ind,
                                              const int* __restrict__ ct_img,
                                              float* __restrict__ points1,
                                              float* __restrict__ out0) {
    int i = blockIdx.x;
    int t = threadIdx.x;              // t = 2*p + c
    int ind = ct_ind[i];
    int x = ind % WIMG, y = ind / WIMG;
    int b = ct_img[i];
    int p = t >> 1, c = t & 1;
    float off = whp[(((size_t)b * 2 * NPOINT + t) * HIMG + y) * WIMG + x];
    float ctc = (c == 0) ? (float)x : (float)y;
    float ip = off * 10.0f + ctc;
    points1[((size_t)i * 129 + 1 + p) * 2 + c] = ip;
    if (t < 2) points1[(size_t)i * 129 * 2 + t] = (t == 0) ? (float)x : (float)y;
    out0[((size_t)i * NPOINT + p) * 2 + c] = ip * 4.0f;
}

// ---------------- conv 3x3 (64->256) + relu, one image, NCHW f32 in -> (16384 px, 256 oc) bf16 out
// grid (256 tiles of 8x8, 4 oc-groups), block 256
__global__ __launch_bounds__(256) void k_conv3x3(const float* __restrict__ in,
                                                 const float* __restrict__ wT,   // (576,256) f32
                                                 const float* __restrict__ bias, // (256) f32
                                                 u16* __restrict__ out,          // (16384,256) bf16
                                                 int b) {
    const int ICC = 8;
    __shared__ float s_in[ICC][10][12];   // halo tile, width padded to 12
    __shared__ float s_w[ICC * 9][64];
    int tid = threadIdx.x;
    int tile = blockIdx.x;
    int ocg = blockIdx.y;
    int ty0 = (tile >> 4) * 8;
    int tx0 = (tile & 15) * 8;
    int ty = tid >> 4, tx = tid & 15;
    int py = ty >> 1;
    int px0 = (ty & 1) * 4;
    float acc[4][4] = {{0.f}};

    for (int ic0 = 0; ic0 < CIN; ic0 += ICC) {
        __syncthreads();
        for (int idx = tid; idx < ICC * 100; idx += 256) {
            int ic = idx / 100, r = idx % 100;
            int rr = r / 10, cc = r % 10;
            int iy = ty0 + rr - 1, ix = tx0 + cc - 1;
            float v = 0.f;
            if (iy >= 0 && iy < HIMG && ix >= 0 && ix < WIMG)
                v = in[(((size_t)b * CIN + ic0 + ic) * HIMG + iy) * WIMG + ix];
            s_in[ic][rr][cc] = v;
        }
        for (int idx = tid; idx < ICC * 9 * 64; idx += 256) {
            int kr = idx >> 6, oc = idx & 63;
            s_w[kr][oc] = wT[(size_t)(ic0 * 9 + kr) * 256 + ocg * 64 + oc];
        }
        __syncthreads();
        for (int ic = 0; ic < ICC; ++ic) {
            #pragma unroll
            for (int ky = 0; ky < 3; ++ky) {
                const float* row = &s_in[ic][py + ky][px0];
                float4 lo = *(const float4*)(row);
                float4 hi = *(const float4*)(row + 4);
                float r8[8] = {lo.x, lo.y, lo.z, lo.w, hi.x, hi.y, hi.z, hi.w};
                #pragma unroll
                for (int kx = 0; kx < 3; ++kx) {
                    float4 wv = *(const float4*)&s_w[ic * 9 + ky * 3 + kx][tx * 4];
                    #pragma unroll
                    for (int i = 0; i < 4; ++i) {
                        float a = r8[kx + i];
                        acc[i][0] = fmaf(a, wv.x, acc[i][0]);
                        acc[i][1] = fmaf(a, wv.y, acc[i][1]);
                        acc[i][2] = fmaf(a, wv.z, acc[i][2]);
                        acc[i][3] = fmaf(a, wv.w, acc[i][3]);
                    }
                }
            }
        }
    }
    float bj0 = bias[ocg * 64 + tx * 4 + 0];
    float bj1 = bias[ocg * 64 + tx * 4 + 1];
    float bj2 = bias[ocg * 64 + tx * 4 + 2];
    float bj3 = bias[ocg * 64 + tx * 4 + 3];
    #pragma unroll
    for (int i = 0; i < 4; ++i) {
        int y = ty0 + py, x = tx0 + px0 + i;
        size_t base = ((size_t)(y * WIMG + x)) * 256 + ocg * 64 + tx * 4;
        ushort4 st;
        st.x = f2bf(fmaxf(acc[i][0] + bj0, 0.f));
        st.y = f2bf(fmaxf(acc[i][1] + bj1, 0.f));
        st.z = f2bf(fmaxf(acc[i][2] + bj2, 0.f));
        st.w = f2bf(fmaxf(acc[i][3] + bj3, 0.f));
        *(ushort4*)(out + base) = st;
    }
}

// ---------------- generic GEMM: C(MxN) = A(MxK, bf16) @ B(KxN, f32) + bias(f32) -> C bf16
// M % 64 == 0, N % 64 == 0, K % 16 == 0. bias length nbias (cols >= nbias get +0).
__global__ __launch_bounds__(256) void k_gemm(const u16* __restrict__ A,
                                              const float* __restrict__ Bm,
                                              const float* __restrict__ bias, int nbias,
                                              u16* __restrict__ C,
                                              int M, int N, int K) {
    __shared__ float sA[16][64];
    __shared__ float sB[16][64];
    int tid = threadIdx.x;
    int ty = tid >> 4, tx = tid & 15;
    int m0 = blockIdx.x * 64, n0 = blockIdx.y * 64;
    int a_m = tid >> 2, a_k = (tid & 3) * 4;
    int b_k = tid >> 4, b_n = (tid & 15) * 4;
    const u16* Aptr = A + (size_t)(m0 + a_m) * K + a_k;
    const float* Bptr = Bm + (size_t)b_k * N + n0 + b_n;
    float acc[4][4] = {{0.f}};
    for (int kk = 0; kk < K; kk += 16) {
        ushort4 av = *(const ushort4*)(Aptr + kk);
        float4 bv = *(const float4*)(Bptr + (size_t)kk * N);
        __syncthreads();
        sA[a_k + 0][a_m] = bf2f(av.x);
        sA[a_k + 1][a_m] = bf2f(av.y);
        sA[a_k + 2][a_m] = bf2f(av.z);
        sA[a_k + 3][a_m] = bf2f(av.w);
        *(float4*)&sB[b_k][b_n] = bv;
        __syncthreads();
        #pragma unroll
        for (int k = 0; k < 16; ++k) {
            float4 a4 = *(const float4*)&sA[k][ty * 4];
            float4 b4 = *(const float4*)&sB[k][tx * 4];
            acc[0][0] = fmaf(a4.x, b4.x, acc[0][0]);
            acc[0][1] = fmaf(a4.x, b4.y, acc[0][1]);
            acc[0][2] = fmaf(a4.x, b4.z, acc[0][2]);
            acc[0][3] = fmaf(a4.x, b4.w, acc[0][3]);
            acc[1][0] = fmaf(a4.y, b4.x, acc[1][0]);
            acc[1][1] = fmaf(a4.y, b4.y, acc[1][1]);
            acc[1][2] = fmaf(a4.y, b4.z, acc[1][2]);
            acc[1][3] = fmaf(a4.y, b4.w, acc[1][3]);
            acc[2][0] = fmaf(a4.z, b4.x, acc[2][0]);
            acc[2][1] = fmaf(a4.z, b4.y, acc[2][1]);
            acc[2][2] = fmaf(a4.z, b4.z, acc[2][2]);
            acc[2][3] = fmaf(a4.z, b4.w, acc[2][3]);
            acc[3][0] = fmaf(a4.w, b4.x, acc[3][0]);
            acc[3][1] = fmaf(a4.w, b4.y, acc[3][1]);
            acc[3][2] = fmaf(a4.w, b4.z, acc[3][2]);
            acc[3][3] = fmaf(a4.w, b4.w, acc[3][3]);
        }
    }
    int nb = n0 + tx * 4;
    float b0 = (nb + 0 < nbias) ? bias[nb + 0] : 0.f;
    float b1 = (nb + 1 < nbias) ? bias[nb + 1] : 0.f;
    float b2 = (nb + 2 < nbias) ? bias[nb + 2] : 0.f;
    float b3 = (nb + 3 < nbias) ? bias[nb + 3] : 0.f;
    #pragma unroll
    for (int i = 0; i < 4; ++i) {
        int m = m0 + ty * 4 + i;
        ushort4 st;
        st.x = f2bf(acc[i][0] + b0);
        st.y = f2bf(acc[i][1] + b1);
        st.z = f2bf(acc[i][2] + b2);
        st.w = f2bf(acc[i][3] + b3);
        *(ushort4*)(C + (size_t)m * N + nb) = st;
    }
}

// ---------------- normalize_poly -> x[...,254:256] (bf16) ----------------
__global__ __launch_bounds__(256) void k_norm(const float* __restrict__ pts,
                                              u16* __restrict__ xout, int P) {
    int i = blockIdx.x, t = threadIdx.x;
    __shared__ float sx[256], sy[256];
    float px = 0.f, py = 0.f;
    if (t < P) {
        px = pts[((size_t)i * P + t) * 2 + 0];
        py = pts[((size_t)i * P + t) * 2 + 1];
    }
    sx[t] = px; sy[t] = py;
    __syncthreads();
    for (int s = 128; s > 0; s >>= 1) {
        if (t < s) { sx[t] += sx[t + s]; sy[t] += sy[t + s]; }
        __syncthreads();
    }
    float mx = sx[0] / (float)P, my = sy[0] / (float)P;
    __syncthreads();
    float ax = 0.f;
    if (t < P) ax = fmaxf(fabsf(px - mx), fabsf(py - my));
    sx[t] = ax;
    __syncthreads();
    for (int s = 128; s > 0; s >>= 1) {
        if (t < s) sx[t] = fmaxf(sx[t], sx[t + s]);
        __syncthreads();
    }
    float scale = sx[0] + 1e-6f;
    if (t < P) {
        size_t base = ((size_t)i * P + t) * 256;
        xout[base + 254] = f2bf((px - mx) / scale);
        xout[base + 255] = f2bf((py - my) / scale);
    }
}

// ---------------- bilinear sample (pixel-major bf16 feat, 254 ch) -> x[...,0:254] bf16
__global__ __launch_bounds__(256) void k_sample(const u16* __restrict__ feat,  // (8*16384,256) cols 254/255 zero
                                                const float* __restrict__ pts,
                                                const int* __restrict__ ct_img,
                                                u16* __restrict__ xout, int P) {
    int i = blockIdx.x, p = blockIdx.y, c = threadIdx.x;
    if (c >= 254) return;
    float px = pts[((size_t)i * P + p) * 2 + 0];
    float py = pts[((size_t)i * P + p) * 2 + 1];
    int b = ct_img[i];
    float ix = px - 0.5f, iy = py - 0.5f;
    float x0f = floorf(ix), y0f = floorf(iy);
    float wx = ix - x0f, wy = iy - y0f;
    int x0 = (int)x0f, y0 = (int)y0f;
    float acc = 0.f;
    #pragma unroll
    for (int dy = 0; dy < 2; ++dy) {
        #pragma unroll
        for (int dx = 0; dx < 2; ++dx) {
            int xx = x0 + dx, yy = y0 + dy;
            float w = (dx ? wx : 1.f - wx) * (dy ? wy : 1.f - wy);
            if (xx >= 0 && xx < WIMG && yy >= 0 && yy < HIMG) {
                acc = fmaf(w, bf2f(feat[(((size_t)b * HIMG + yy) * WIMG + xx) * 256 + c]), acc);
            }
        }
    }
    xout[((size_t)i * P + p) * 256 + c] = f2bf(acc);
}

// ---------------- attention (one row per thread, online softmax) ----------------
// qkv is chunk-local (instances i0..); obuf is global (aliases xbuf rows)
__global__ void k_attn(const u16* __restrict__ qkv,  // (chunk_inst*P, 768) bf16
                       u16* __restrict__ obuf,       // global (rows i*P+t, 256) bf16
                       int P, int i0) {
    int il = blockIdx.x, h = blockIdx.y;
    int ig = i0 + il;
    int t = threadIdx.x;
    __shared__ float sk[129][32];
    __shared__ float sv[129][32];
    for (int idx = t; idx < P * 32; idx += blockDim.x) {
        int r = idx >> 5, d = idx & 31;
        size_t base = ((size_t)il * P + r) * 768 + h * 32 + d;
        sk[r][d] = bf2f(qkv[base + 256]);
        sv[r][d] = bf2f(qkv[base + 512]);
    }
    __syncthreads();
    if (t >= P) return;
    float q[32];
    size_t qb = ((size_t)il * P + t) * 768 + h * 32;
    #pragma unroll
    for (int d = 0; d < 32; ++d) q[d] = bf2f(qkv[qb + d]) * 0.17677669529663689f;
    float m = -1e30f, l = 0.f;
    float O[32];
    #pragma unroll
    for (int d = 0; d < 32; ++d) O[d] = 0.f;
    for (int c = 0; c < P; ++c) {
        float s = 0.f;
        #pragma unroll
        for (int j = 0; j < 8; ++j) {
            float4 kv = *(const float4*)&sk[c][j * 4];
            s = fmaf(q[j * 4 + 0], kv.x, s);
            s = fmaf(q[j * 4 + 1], kv.y, s);
            s = fmaf(q[j * 4 + 2], kv.z, s);
            s = fmaf(q[j * 4 + 3], kv.w, s);
        }
        float nm = fmaxf(m, s);
        float al = __expf(m - nm);
        float e = __expf(s - nm);
        l = l * al + e;
        #pragma unroll
        for (int j = 0; j < 8; ++j) {
            float4 vv = *(const float4*)&sv[c][j * 4];
            O[j * 4 + 0] = fmaf(O[j * 4 + 0], al, e * vv.x);
            O[j * 4 + 1] = fmaf(O[j * 4 + 1], al, e * vv.y);
            O[j * 4 + 2] = fmaf(O[j * 4 + 2], al, e * vv.z);
            O[j * 4 + 3] = fmaf(O[j * 4 + 3], al, e * vv.w);
        }
        m = nm;
    }
    float inv = 1.f / l;
    size_t ob = ((size_t)ig * P + t) * 256 + h * 32;
    #pragma unroll
    for (int d = 0; d < 32; ++d) obuf[ob + d] = f2bf(O[d] * inv);
}

// ---------------- head projection + poly update ----------------
// stage 1: global rows m = row0 + bid*4 + wave = i*129+p, keep p>=1: coarse = off*4 + init
__global__ __launch_bounds__(256) void k_head1(const u16* __restrict__ obuf,
                                               const float* __restrict__ W2,
                                               const float* __restrict__ b2,
                                               const float* __restrict__ pts1,
                                               float* __restrict__ coarse,
                                               float* __restrict__ out1,
                                               int row0) {
    int wave = threadIdx.x >> 6, lane = threadIdx.x & 63;
    int m = row0 + blockIdx.x * 4 + wave;
    const u16* orow = obuf + (size_t)m * 256;
    ushort4 u = *(const ushort4*)(orow + lane * 4);
    float4 w0 = *(const float4*)(W2 + lane * 8);
    float4 w1 = *(const float4*)(W2 + lane * 8 + 4);
    float c0 = bf2f(u.x), c1 = bf2f(u.y), c2 = bf2f(u.z), c3 = bf2f(u.w);
    float s0 = c0 * w0.x + c1 * w0.z + c2 * w1.x + c3 * w1.z;
    float s1 = c0 * w0.y + c1 * w0.w + c2 * w1.y + c3 * w1.w;
    for (int off = 32; off > 0; off >>= 1) {
        s0 += __shfl_down(s0, off);
        s1 += __shfl_down(s1, off);
    }
    if (lane == 0) {
        int i = m / 129, p = m % 129;
        if (p > 0) {
            float o0 = s0 + b2[0], o1 = s1 + b2[1];
            float i0 = pts1[(size_t)m * 2 + 0];
            float i1 = pts1[(size_t)m * 2 + 1];
            float cc0 = o0 * 4.f + i0, cc1 = o1 * 4.f + i1;
            size_t cm = (size_t)i * 128 + (p - 1);
            coarse[cm * 2 + 0] = cc0;
            coarse[cm * 2 + 1] = cc1;
            out1[cm * 2 + 0] = cc0 * 4.f;
            out1[cm * 2 + 1] = cc1 * 4.f;
        }
    }
}

// stage 2: global rows m = row0 + bid*4 + wave = i*128+p; final = off + coarse
__global__ __launch_bounds__(256) void k_head2(const u16* __restrict__ obuf,
                                               const float* __restrict__ W2,
                                               const float* __restrict__ b2,
                                               const float* __restrict__ coarse,
                                               float* __restrict__ out2,
                                               int row0) {
    int wave = threadIdx.x >> 6, lane = threadIdx.x & 63;
    int m = row0 + blockIdx.x * 4 + wave;
    const u16* orow = obuf + (size_t)m * 256;
    ushort4 u = *(const ushort4*)(orow + lane * 4);
    float4 w0 = *(const float4*)(W2 + lane * 8);
    float4 w1 = *(const float4*)(W2 + lane * 8 + 4);
    float c0 = bf2f(u.x), c1 = bf2f(u.y), c2 = bf2f(u.z), c3 = bf2f(u.w);
    float s0 = c0 * w0.x + c1 * w0.z + c2 * w1.x + c3 * w1.z;
    float s1 = c0 * w0.y + c1 * w0.w + c2 * w1.y + c3 * w1.w;
    for (int off = 32; off > 0; off >>= 1) {
        s0 += __shfl_down(s0, off);
        s1 += __shfl_down(s1, off);
    }
    if (lane == 0) {
        float f0 = s0 + b2[0] + coarse[(size_t)m * 2 + 0];
        float f1 = s1 + b2[1] + coarse[(size_t)m * 2 + 1];
        out2[(size_t)m * 2 + 0] = f0 * 4.f;
        out2[(size_t)m * 2 + 1] = f1 * 4.f;
    }
}

// ---------------- host ----------------
extern "C" void kernel_launch(void* const* d_in, const int* in_sizes, int n_in,
                              void* d_out, int out_size, void* d_ws, size_t ws_size,
                              hipStream_t stream) {
    const float* cnn     = (const float*)d_in[0];
    const float* whp     = (const float*)d_in[1];
    const int*   ct_ind  = (const int*)d_in[2];
    const int*   ct_img  = (const int*)d_in[3];
    const float* f1_w1   = (const float*)d_in[4];
    const float* f1_b1   = (const float*)d_in[5];
    const float* f1_w2   = (const float*)d_in[6];
    const float* f1_b2   = (const float*)d_in[7];
    const float* f2_w1   = (const float*)d_in[8];
    const float* f2_b1   = (const float*)d_in[9];
    const float* f2_w2   = (const float*)d_in[10];
    const float* f2_b2   = (const float*)d_in[11];
    const float* c1_wqkv = (const float*)d_in[12];
    const float* c1_bqkv = (const float*)d_in[13];
    const float* c1_wo   = (const float*)d_in[14];
    const float* c1_bo   = (const float*)d_in[15];
    const float* c1_wh   = (const float*)d_in[16];
    const float* c1_bh   = (const float*)d_in[17];
    const float* c2_wqkv = (const float*)d_in[18];
    const float* c2_bqkv = (const float*)d_in[19];
    const float* c2_wo   = (const float*)d_in[20];
    const float* c2_bo   = (const float*)d_in[21];
    const float* c2_wh   = (const float*)d_in[22];
    const float* c2_bh   = (const float*)d_in[23];

    // ws layout, total ~129.0 MB
    char* ws = (char*)d_ws;
    float* points1 = (float*)(ws + 0);                // 512*129*2 f32   (528384 B)
    float* coarse  = (float*)(ws + 528384);           // 512*128*2 f32   (524288 B)
    float* W2_1    = (float*)(ws + 1052672);          // 512 f32
    float* b2_1    = (float*)(ws + 1054720);          // 2 f32 (pad 256)
    float* W2_2    = (float*)(ws + 1054976);
    float* b2_2    = (float*)(ws + 1057024);
    float* wT1a    = (float*)(ws + 1057280);          // 576*256 f32     (589824 B)
    float* wT1b    = (float*)(ws + 1647104);
    float* wT2a    = (float*)(ws + 2236928);          // 256*256 f32     (262144 B)
    float* wT2b    = (float*)(ws + 2499072);
    u16*   feat    = (u16*)(ws + 2761216);            // 8*16384*256 bf16 (67108864 B)
    u16*   xbuf    = (u16*)(ws + 69870080);           // 66048*256 bf16; also obuf alias (33816576 B)
    u16*   scratch = (u16*)(ws + 103686656);          // relu chunk (8.4MB) / qkv chunk (25.4MB)
    // end: 129049088 B

    float* out0 = (float*)d_out;
    float* out1 = out0 + 131072;
    float* out2 = out0 + 262144;

    // prep
    k_transpose_w1<<<576, 256, 0, stream>>>(f1_w1, wT1a);
    k_transpose_w1<<<576, 256, 0, stream>>>(f2_w1, wT1b);
    k_transpose_w2<<<256, 256, 0, stream>>>(f1_w2, wT2a);
    k_transpose_w2<<<256, 256, 0, stream>>>(f2_w2, wT2b);
    k_headfuse<<<2, 256, 0, stream>>>(c1_wo, c1_bo, c1_wh, c1_bh, W2_1, b2_1);
    k_headfuse<<<2, 256, 0, stream>>>(c2_wo, c2_bo, c2_wh, c2_bh, W2_2, b2_2);

    k_init<<<NINST, 256, 0, stream>>>(whp, ct_ind, ct_img, points1, out0);

    // ---- stage 1: feat1 (per-image conv -> 1x1 gemm into feat) ----
    for (int b = 0; b < BIMG; ++b) {
        k_conv3x3<<<dim3(256, 4), 256, 0, stream>>>(cnn, wT1a, f1_b1, scratch, b);
        k_gemm<<<dim3(256, 4), 256, 0, stream>>>(scratch, wT2a, f1_b2, 254,
                                                 feat + (size_t)b * 16384 * 256,
                                                 16384, 256, 256);
    }
    k_norm<<<NINST, 256, 0, stream>>>(points1, xbuf, 129);
    k_sample<<<dim3(NINST, 129), 256, 0, stream>>>(feat, points1, ct_img, xbuf, 129);
    // qkv + attn + head, chunks of 128 instances (16512 rows)
    for (int c = 0; c < 4; ++c) {
        int row0 = c * 128 * 129;
        k_gemm<<<dim3(258, 12), 256, 0, stream>>>(xbuf + (size_t)row0 * 256, c1_wqkv, c1_bqkv, 768,
                                                  scratch, 16512, 768, 256);
        k_attn<<<dim3(128, 8), 192, 0, stream>>>(scratch, xbuf, 129, c * 128);
        k_head1<<<4128, 256, 0, stream>>>(xbuf, W2_1, b2_1, points1, coarse, out1, row0);
    }

    // ---- stage 2: feat2 (recompute into same feat buffer) ----
    for (int b = 0; b < BIMG; ++b) {
        k_conv3x3<<<dim3(256, 4), 256, 0, stream>>>(cnn, wT1b, f2_b1, scratch, b);
        k_gemm<<<dim3(256, 4), 256, 0, stream>>>(scratch, wT2b, f2_b2, 254,
                                                 feat + (size_t)b * 16384 * 256,
                                                 16384, 256, 256);
    }
    k_norm<<<NINST, 256, 0, stream>>>(coarse, xbuf, 128);
    k_sample<<<dim3(NINST, 128), 256, 0, stream>>>(feat, coarse, ct_img, xbuf, 128);
    for (int c = 0; c < 4; ++c) {
        int row0 = c * 128 * 128;
        k_gemm<<<dim3(256, 12), 256, 0, stream>>>(xbuf + (size_t)row0 * 256, c2_wqkv, c2_bqkv, 768,
                                                  scratch, 16384, 768, 256);
        k_attn<<<dim3(128, 8), 128, 0, stream>>>(scratch, xbuf, 128, c * 128);
        k_head2<<<4096, 256, 0, stream>>>(xbuf, W2_2, b2_2, coarse, out2, row0);
    }
}

// Round 4
// 1956.698 us; speedup vs baseline: 1.6845x; 1.6845x over previous
//
#include <hip/hip_runtime.h>
#include <hip/hip_bf16.h>

// ---------------- common helpers ----------------
typedef unsigned short u16;
typedef float  f32x4 __attribute__((ext_vector_type(4)));
typedef short  s16x8 __attribute__((ext_vector_type(8)));

__device__ __forceinline__ float bf2f(u16 u) {
    return __uint_as_float(((unsigned int)u) << 16);
}
__device__ __forceinline__ u16 f2bf(float f) {
    unsigned int x = __float_as_uint(f);
    unsigned int r = x + 0x7fffu + ((x >> 16) & 1u);
    return (u16)(r >> 16);
}

#define WIMG 128
#define HIMG 128
#define BIMG 8
#define CIN  64
#define NPOINT 128
#define NINST 512

// ---------------- weight conversion (f32 -> bf16, MFMA-friendly layouts) ----------------
// w1 (256 oc, 64 ic, 3, 3) -> wb1[oc][kp*64+ic], kp = ky*3+kx  (Bt layout: N=256 x K=576)
__global__ __launch_bounds__(256) void k_cvt_w1(const float* __restrict__ w,
                                                u16* __restrict__ wb) {
    int idx = blockIdx.x * 256 + threadIdx.x;   // 147456
    int oc = idx / 576, r = idx % 576;
    int kp = r >> 6, ic = r & 63;               // out k-index = kp*64+ic
    wb[idx] = f2bf(w[oc * 576 + ic * 9 + kp]);
}

// w2 (254 oc, 256 ic) -> wb2[oc][ic] bf16, rows oc>=254 zero  (Bt: 256 x 256)
__global__ __launch_bounds__(256) void k_cvt_w2(const float* __restrict__ w,
                                                u16* __restrict__ wb) {
    int idx = blockIdx.x * 256 + threadIdx.x;   // 65536
    int oc = idx >> 8, ic = idx & 255;
    wb[idx] = (oc < 254) ? f2bf(w[oc * 256 + ic]) : (u16)0;
}

// wqkv (256 k, 768 n) -> wqT[n][k] bf16  (Bt: 768 x 256)
__global__ __launch_bounds__(256) void k_cvt_wqkv(const float* __restrict__ w,
                                                  u16* __restrict__ wb) {
    int idx = blockIdx.x * 256 + threadIdx.x;   // 196608
    int n = idx >> 8, k = idx & 255;
    wb[idx] = f2bf(w[k * 768 + n]);
}

// W2 = wo @ whead (256x2), b2 = bo @ whead + bhead (2), all f32
__global__ __launch_bounds__(256) void k_headfuse(const float* __restrict__ wo,
                                                  const float* __restrict__ bo,
                                                  const float* __restrict__ whead,
                                                  const float* __restrict__ bhead,
                                                  float* __restrict__ W2,
                                                  float* __restrict__ b2) {
    int idx = blockIdx.x * 256 + threadIdx.x;   // 512 total
    if (idx < 512) {
        int c = idx >> 1, j = idx & 1;
        float s = 0.f;
        for (int t = 0; t < 256; ++t)
            s = fmaf(wo[c * 256 + t], whead[t * 2 + j], s);
        W2[idx] = s;
    }
    if (idx < 2) {
        float s = bhead[idx];
        for (int t = 0; t < 256; ++t)
            s = fmaf(bo[t], whead[t * 2 + idx], s);
        b2[idx] = s;
    }
}

// ---------------- init polys ----------------
__global__ __launch_bounds__(256) void k_init(const float* __restrict__ whp,
                                              const int* __restrict__ ct_ind,
                                              const int* __restrict__ ct_img,
                                              float* __restrict__ points1,
                                              float* __restrict__ out0) {
    int i = blockIdx.x;
    int t = threadIdx.x;              // t = 2*p + c
    int ind = ct_ind[i];
    int x = ind % WIMG, y = ind / WIMG;
    int b = ct_img[i];
    int p = t >> 1, c = t & 1;
    float off = whp[(((size_t)b * 2 * NPOINT + t) * HIMG + y) * WIMG + x];
    float ctc = (c == 0) ? (float)x : (float)y;
    float ip = off * 10.0f + ctc;
    points1[((size_t)i * 129 + 1 + p) * 2 + c] = ip;
    if (t < 2) points1[(size_t)i * 129 * 2 + t] = (t == 0) ? (float)x : (float)y;
    out0[((size_t)i * NPOINT + p) * 2 + c] = ip * 4.0f;
}

// ---------------- MFMA NT GEMM: C(MxN bf16) = act(A(MxK bf16) @ Bt(NxK bf16)^T + bias) ----
// M%128==0, N%128==0, K%32==0. bias f32 len nbias (cols>=nbias get +0). relu flag.
__global__ __launch_bounds__(256) void k_gemm_mfma(const u16* __restrict__ A,
                                                   const u16* __restrict__ Bt,
                                                   const float* __restrict__ bias, int nbias,
                                                   u16* __restrict__ C,
                                                   int M, int N, int K, int relu) {
    __shared__ u16 sA[128 * 40];   // rows padded to 40 elems (80 B, 16B-aligned)
    __shared__ u16 sB[128 * 40];
    int tid = threadIdx.x;
    int wave = tid >> 6, lane = tid & 63;
    int quad = lane >> 4, l16 = lane & 15;
    int m0 = blockIdx.x * 128, n0 = blockIdx.y * 128;
    int wm = (wave >> 1) * 64, wn = (wave & 1) * 64;
    f32x4 acc[4][4];
    #pragma unroll
    for (int a = 0; a < 4; ++a)
        #pragma unroll
        for (int b = 0; b < 4; ++b)
            #pragma unroll
            for (int q = 0; q < 4; ++q) acc[a][b][q] = 0.f;

    for (int kk = 0; kk < K; kk += 32) {
        __syncthreads();
        #pragma unroll
        for (int c = 0; c < 2; ++c) {
            int ch = c * 256 + tid;           // 512 chunks of 16 B
            int row = ch >> 2, sub = ch & 3;
            *(uint4*)&sA[row * 40 + sub * 8] =
                *(const uint4*)&A[(size_t)(m0 + row) * K + kk + sub * 8];
            *(uint4*)&sB[row * 40 + sub * 8] =
                *(const uint4*)&Bt[(size_t)(n0 + row) * K + kk + sub * 8];
        }
        __syncthreads();
        s16x8 aF[4], bF[4];
        #pragma unroll
        for (int mt = 0; mt < 4; ++mt)
            aF[mt] = *(const s16x8*)&sA[(wm + mt * 16 + l16) * 40 + quad * 8];
        #pragma unroll
        for (int nt = 0; nt < 4; ++nt)
            bF[nt] = *(const s16x8*)&sB[(wn + nt * 16 + l16) * 40 + quad * 8];
        #pragma unroll
        for (int mt = 0; mt < 4; ++mt)
            #pragma unroll
            for (int nt = 0; nt < 4; ++nt)
                acc[mt][nt] = __builtin_amdgcn_mfma_f32_16x16x32_bf16(
                    aF[mt], bF[nt], acc[mt][nt], 0, 0, 0);
    }
    #pragma unroll
    for (int nt = 0; nt < 4; ++nt) {
        int col = n0 + wn + nt * 16 + l16;
        float bv = (col < nbias) ? bias[col] : 0.f;
        #pragma unroll
        for (int mt = 0; mt < 4; ++mt) {
            #pragma unroll
            for (int r = 0; r < 4; ++r) {
                int row = m0 + wm + mt * 16 + quad * 4 + r;
                float v = acc[mt][nt][r] + bv;
                if (relu) v = fmaxf(v, 0.f);
                C[(size_t)row * N + col] = f2bf(v);
            }
        }
    }
}

// ---------------- implicit-GEMM 3x3 conv (64->256) + bias + relu, MFMA ----------------
// in NCHW f32 (one image b), wb1 Bt layout (256 oc x 576 k), k=(ky*3+kx)*64+ic.
// out (16384 px, 256 oc) bf16. grid (128 y-rows, 2 oc-halves), block 256.
__global__ __launch_bounds__(256) void k_conv_mfma(const float* __restrict__ in,
                                                   const u16* __restrict__ wb1,
                                                   const float* __restrict__ bias,
                                                   u16* __restrict__ out,
                                                   int b) {
    __shared__ u16 sA[128 * 40];
    __shared__ u16 sB[128 * 40];
    int tid = threadIdx.x;
    int wave = tid >> 6, lane = tid & 63;
    int quad = lane >> 4, l16 = lane & 15;
    int y = blockIdx.x;                 // m0 = y*128 (one image row per block)
    int m0 = y * 128;
    int n0 = blockIdx.y * 128;
    int wm = (wave >> 1) * 64, wn = (wave & 1) * 64;
    const float* inb = in + (size_t)b * CIN * HIMG * WIMG;
    f32x4 acc[4][4];
    #pragma unroll
    for (int a = 0; a < 4; ++a)
        #pragma unroll
        for (int c = 0; c < 4; ++c)
            #pragma unroll
            for (int q = 0; q < 4; ++q) acc[a][c][q] = 0.f;

    for (int kk = 0; kk < 576; kk += 32) {
        int kp = kk >> 6;               // kernel position 0..8
        int ic0 = kk & 63;              // 0 or 32
        int ky = kp / 3, kx = kp % 3;
        int iy = y + ky - 1;
        bool vy = (iy >= 0) && (iy < HIMG);
        __syncthreads();
        // stage B tile (128 oc x 32 k)
        #pragma unroll
        for (int c = 0; c < 2; ++c) {
            int ch = c * 256 + tid;
            int row = ch >> 2, sub = ch & 3;
            *(uint4*)&sB[row * 40 + sub * 8] =
                *(const uint4*)&wb1[(size_t)(n0 + row) * 576 + kk + sub * 8];
        }
        // stage A tile (128 px x 32 ic) via in-LDS im2col
        #pragma unroll
        for (int j = 0; j < 16; ++j) {
            int e = j * 256 + tid;        // 4096 elems
            int row = e & 127, kidx = e >> 7;
            int ix = row + kx - 1;
            float v = 0.f;
            if (vy && ix >= 0 && ix < WIMG)
                v = inb[(size_t)(ic0 + kidx) * (HIMG * WIMG) + iy * WIMG + ix];
            sA[row * 40 + kidx] = f2bf(v);
        }
        __syncthreads();
        s16x8 aF[4], bF[4];
        #pragma unroll
        for (int mt = 0; mt < 4; ++mt)
            aF[mt] = *(const s16x8*)&sA[(wm + mt * 16 + l16) * 40 + quad * 8];
        #pragma unroll
        for (int nt = 0; nt < 4; ++nt)
            bF[nt] = *(const s16x8*)&sB[(wn + nt * 16 + l16) * 40 + quad * 8];
        #pragma unroll
        for (int mt = 0; mt < 4; ++mt)
            #pragma unroll
            for (int nt = 0; nt < 4; ++nt)
                acc[mt][nt] = __builtin_amdgcn_mfma_f32_16x16x32_bf16(
                    aF[mt], bF[nt], acc[mt][nt], 0, 0, 0);
    }
    #pragma unroll
    for (int nt = 0; nt < 4; ++nt) {
        int col = n0 + wn + nt * 16 + l16;
        float bv = bias[col];
        #pragma unroll
        for (int mt = 0; mt < 4; ++mt) {
            #pragma unroll
            for (int r = 0; r < 4; ++r) {
                int row = m0 + wm + mt * 16 + quad * 4 + r;
                float v = fmaxf(acc[mt][nt][r] + bv, 0.f);
                out[(size_t)row * 256 + col] = f2bf(v);
            }
        }
    }
}

// ---------------- normalize_poly -> x[...,254:256] (bf16) ----------------
__global__ __launch_bounds__(256) void k_norm(const float* __restrict__ pts,
                                              u16* __restrict__ xout, int P) {
    int i = blockIdx.x, t = threadIdx.x;
    __shared__ float sx[256], sy[256];
    float px = 0.f, py = 0.f;
    if (t < P) {
        px = pts[((size_t)i * P + t) * 2 + 0];
        py = pts[((size_t)i * P + t) * 2 + 1];
    }
    sx[t] = px; sy[t] = py;
    __syncthreads();
    for (int s = 128; s > 0; s >>= 1) {
        if (t < s) { sx[t] += sx[t + s]; sy[t] += sy[t + s]; }
        __syncthreads();
    }
    float mx = sx[0] / (float)P, my = sy[0] / (float)P;
    __syncthreads();
    float ax = 0.f;
    if (t < P) ax = fmaxf(fabsf(px - mx), fabsf(py - my));
    sx[t] = ax;
    __syncthreads();
    for (int s = 128; s > 0; s >>= 1) {
        if (t < s) sx[t] = fmaxf(sx[t], sx[t + s]);
        __syncthreads();
    }
    float scale = sx[0] + 1e-6f;
    if (t < P) {
        size_t base = ((size_t)i * P + t) * 256;
        xout[base + 254] = f2bf((px - mx) / scale);
        xout[base + 255] = f2bf((py - my) / scale);
    }
}

// ---------------- bilinear sample (pixel-major bf16 feat, 254 ch) -> x[...,0:254] bf16
__global__ __launch_bounds__(256) void k_sample(const u16* __restrict__ feat,
                                                const float* __restrict__ pts,
                                                const int* __restrict__ ct_img,
                                                u16* __restrict__ xout, int P) {
    int i = blockIdx.x, p = blockIdx.y, c = threadIdx.x;
    if (c >= 254) return;
    float px = pts[((size_t)i * P + p) * 2 + 0];
    float py = pts[((size_t)i * P + p) * 2 + 1];
    int b = ct_img[i];
    float ix = px - 0.5f, iy = py - 0.5f;
    float x0f = floorf(ix), y0f = floorf(iy);
    float wx = ix - x0f, wy = iy - y0f;
    int x0 = (int)x0f, y0 = (int)y0f;
    float acc = 0.f;
    #pragma unroll
    for (int dy = 0; dy < 2; ++dy) {
        #pragma unroll
        for (int dx = 0; dx < 2; ++dx) {
            int xx = x0 + dx, yy = y0 + dy;
            float w = (dx ? wx : 1.f - wx) * (dy ? wy : 1.f - wy);
            if (xx >= 0 && xx < WIMG && yy >= 0 && yy < HIMG) {
                acc = fmaf(w, bf2f(feat[(((size_t)b * HIMG + yy) * WIMG + xx) * 256 + c]), acc);
            }
        }
    }
    xout[((size_t)i * P + p) * 256 + c] = f2bf(acc);
}

// ---------------- attention (one row per thread, online softmax) ----------------
__global__ void k_attn(const u16* __restrict__ qkv,  // (chunk_inst*P, 768) bf16
                       u16* __restrict__ obuf,       // global (rows i*P+t, 256) bf16
                       int P, int i0) {
    int il = blockIdx.x, h = blockIdx.y;
    int ig = i0 + il;
    int t = threadIdx.x;
    __shared__ float sk[129][32];
    __shared__ float sv[129][32];
    for (int idx = t; idx < P * 32; idx += blockDim.x) {
        int r = idx >> 5, d = idx & 31;
        size_t base = ((size_t)il * P + r) * 768 + h * 32 + d;
        sk[r][d] = bf2f(qkv[base + 256]);
        sv[r][d] = bf2f(qkv[base + 512]);
    }
    __syncthreads();
    if (t >= P) return;
    float q[32];
    size_t qb = ((size_t)il * P + t) * 768 + h * 32;
    #pragma unroll
    for (int d = 0; d < 32; ++d) q[d] = bf2f(qkv[qb + d]) * 0.17677669529663689f;
    float m = -1e30f, l = 0.f;
    float O[32];
    #pragma unroll
    for (int d = 0; d < 32; ++d) O[d] = 0.f;
    for (int c = 0; c < P; ++c) {
        float s = 0.f;
        #pragma unroll
        for (int j = 0; j < 8; ++j) {
            float4 kv = *(const float4*)&sk[c][j * 4];
            s = fmaf(q[j * 4 + 0], kv.x, s);
            s = fmaf(q[j * 4 + 1], kv.y, s);
            s = fmaf(q[j * 4 + 2], kv.z, s);
            s = fmaf(q[j * 4 + 3], kv.w, s);
        }
        float nm = fmaxf(m, s);
        float al = __expf(m - nm);
        float e = __expf(s - nm);
        l = l * al + e;
        #pragma unroll
        for (int j = 0; j < 8; ++j) {
            float4 vv = *(const float4*)&sv[c][j * 4];
            O[j * 4 + 0] = fmaf(O[j * 4 + 0], al, e * vv.x);
            O[j * 4 + 1] = fmaf(O[j * 4 + 1], al, e * vv.y);
            O[j * 4 + 2] = fmaf(O[j * 4 + 2], al, e * vv.z);
            O[j * 4 + 3] = fmaf(O[j * 4 + 3], al, e * vv.w);
        }
        m = nm;
    }
    float inv = 1.f / l;
    size_t ob = ((size_t)ig * P + t) * 256 + h * 32;
    #pragma unroll
    for (int d = 0; d < 32; ++d) obuf[ob + d] = f2bf(O[d] * inv);
}

// ---------------- head projection + poly update ----------------
__global__ __launch_bounds__(256) void k_head1(const u16* __restrict__ obuf,
                                               const float* __restrict__ W2,
                                               const float* __restrict__ b2,
                                               const float* __restrict__ pts1,
                                               float* __restrict__ coarse,
                                               float* __restrict__ out1,
                                               int row0) {
    int wave = threadIdx.x >> 6, lane = threadIdx.x & 63;
    int m = row0 + blockIdx.x * 4 + wave;
    const u16* orow = obuf + (size_t)m * 256;
    ushort4 u = *(const ushort4*)(orow + lane * 4);
    float4 w0 = *(const float4*)(W2 + lane * 8);
    float4 w1 = *(const float4*)(W2 + lane * 8 + 4);
    float c0 = bf2f(u.x), c1 = bf2f(u.y), c2 = bf2f(u.z), c3 = bf2f(u.w);
    float s0 = c0 * w0.x + c1 * w0.z + c2 * w1.x + c3 * w1.z;
    float s1 = c0 * w0.y + c1 * w0.w + c2 * w1.y + c3 * w1.w;
    for (int off = 32; off > 0; off >>= 1) {
        s0 += __shfl_down(s0, off);
        s1 += __shfl_down(s1, off);
    }
    if (lane == 0) {
        int i = m / 129, p = m % 129;
        if (p > 0) {
            float o0 = s0 + b2[0], o1 = s1 + b2[1];
            float i0 = pts1[(size_t)m * 2 + 0];
            float i1 = pts1[(size_t)m * 2 + 1];
            float cc0 = o0 * 4.f + i0, cc1 = o1 * 4.f + i1;
            size_t cm = (size_t)i * 128 + (p - 1);
            coarse[cm * 2 + 0] = cc0;
            coarse[cm * 2 + 1] = cc1;
            out1[cm * 2 + 0] = cc0 * 4.f;
            out1[cm * 2 + 1] = cc1 * 4.f;
        }
    }
}

__global__ __launch_bounds__(256) void k_head2(const u16* __restrict__ obuf,
                                               const float* __restrict__ W2,
                                               const float* __restrict__ b2,
                                               const float* __restrict__ coarse,
                                               float* __restrict__ out2,
                                               int row0) {
    int wave = threadIdx.x >> 6, lane = threadIdx.x & 63;
    int m = row0 + blockIdx.x * 4 + wave;
    const u16* orow = obuf + (size_t)m * 256;
    ushort4 u = *(const ushort4*)(orow + lane * 4);
    float4 w0 = *(const float4*)(W2 + lane * 8);
    float4 w1 = *(const float4*)(W2 + lane * 8 + 4);
    float c0 = bf2f(u.x), c1 = bf2f(u.y), c2 = bf2f(u.z), c3 = bf2f(u.w);
    float s0 = c0 * w0.x + c1 * w0.z + c2 * w1.x + c3 * w1.z;
    float s1 = c0 * w0.y + c1 * w0.w + c2 * w1.y + c3 * w1.w;
    for (int off = 32; off > 0; off >>= 1) {
        s0 += __shfl_down(s0, off);
        s1 += __shfl_down(s1, off);
    }
    if (lane == 0) {
        float f0 = s0 + b2[0] + coarse[(size_t)m * 2 + 0];
        float f1 = s1 + b2[1] + coarse[(size_t)m * 2 + 1];
        out2[(size_t)m * 2 + 0] = f0 * 4.f;
        out2[(size_t)m * 2 + 1] = f1 * 4.f;
    }
}

// ---------------- host ----------------
extern "C" void kernel_launch(void* const* d_in, const int* in_sizes, int n_in,
                              void* d_out, int out_size, void* d_ws, size_t ws_size,
                              hipStream_t stream) {
    const float* cnn     = (const float*)d_in[0];
    const float* whp     = (const float*)d_in[1];
    const int*   ct_ind  = (const int*)d_in[2];
    const int*   ct_img  = (const int*)d_in[3];
    const float* f1_w1   = (const float*)d_in[4];
    const float* f1_b1   = (const float*)d_in[5];
    const float* f1_w2   = (const float*)d_in[6];
    const float* f1_b2   = (const float*)d_in[7];
    const float* f2_w1   = (const float*)d_in[8];
    const float* f2_b1   = (const float*)d_in[9];
    const float* f2_w2   = (const float*)d_in[10];
    const float* f2_b2   = (const float*)d_in[11];
    const float* c1_wqkv = (const float*)d_in[12];
    const float* c1_bqkv = (const float*)d_in[13];
    const float* c1_wo   = (const float*)d_in[14];
    const float* c1_bo   = (const float*)d_in[15];
    const float* c1_wh   = (const float*)d_in[16];
    const float* c1_bh   = (const float*)d_in[17];
    const float* c2_wqkv = (const float*)d_in[18];
    const float* c2_bqkv = (const float*)d_in[19];
    const float* c2_wo   = (const float*)d_in[20];
    const float* c2_bo   = (const float*)d_in[21];
    const float* c2_wh   = (const float*)d_in[22];
    const float* c2_bh   = (const float*)d_in[23];

    // ws layout, total ~129.0 MB (round-3 PASS proves this budget fits)
    char* ws = (char*)d_ws;
    float* points1 = (float*)(ws + 0);                // 512*129*2 f32   (528384 B)
    float* coarse  = (float*)(ws + 528384);           // 512*128*2 f32
    float* W2_1    = (float*)(ws + 1052672);          // 512 f32
    float* b2_1    = (float*)(ws + 1054720);
    float* W2_2    = (float*)(ws + 1054976);
    float* b2_2    = (float*)(ws + 1057024);
    u16*   wb1a    = (u16*)(ws + 1057280);            // 256x576 bf16 (294912 B)
    u16*   wb1b    = (u16*)(ws + 1352192);
    u16*   wb2a    = (u16*)(ws + 1647104);            // 256x256 bf16 (131072 B)
    u16*   wb2b    = (u16*)(ws + 1778176);
    u16*   wqT1    = (u16*)(ws + 1909248);            // 768x256 bf16 (393216 B)
    u16*   wqT2    = (u16*)(ws + 2302464);
    u16*   feat    = (u16*)(ws + 2695680);            // 8*16384*256 bf16 (67108864 B)
    u16*   xbuf    = (u16*)(ws + 69804544);           // 66048*256 bf16 (33816576 B); relu_buf alias
    u16*   scratch = (u16*)(ws + 103621120);          // qkv chunk 16512*768 bf16 (25362432 B)
    // end: 128983552 B

    u16* relu_buf = xbuf;   // alias: conv phases never overlap attention phases

    float* out0 = (float*)d_out;
    float* out1 = out0 + 131072;
    float* out2 = out0 + 262144;

    // prep
    k_cvt_w1<<<576, 256, 0, stream>>>(f1_w1, wb1a);
    k_cvt_w1<<<576, 256, 0, stream>>>(f2_w1, wb1b);
    k_cvt_w2<<<256, 256, 0, stream>>>(f1_w2, wb2a);
    k_cvt_w2<<<256, 256, 0, stream>>>(f2_w2, wb2b);
    k_cvt_wqkv<<<768, 256, 0, stream>>>(c1_wqkv, wqT1);
    k_cvt_wqkv<<<768, 256, 0, stream>>>(c2_wqkv, wqT2);
    k_headfuse<<<2, 256, 0, stream>>>(c1_wo, c1_bo, c1_wh, c1_bh, W2_1, b2_1);
    k_headfuse<<<2, 256, 0, stream>>>(c2_wo, c2_bo, c2_wh, c2_bh, W2_2, b2_2);

    k_init<<<NINST, 256, 0, stream>>>(whp, ct_ind, ct_img, points1, out0);

    // ---- stage 1: feat1 = conv3x3(relu) -> 1x1 ----
    for (int b = 0; b < BIMG; ++b) {
        k_conv_mfma<<<dim3(128, 2), 256, 0, stream>>>(cnn, wb1a, f1_b1, relu_buf, b);
        k_gemm_mfma<<<dim3(128, 2), 256, 0, stream>>>(relu_buf, wb2a, f1_b2, 254,
                                                      feat + (size_t)b * 16384 * 256,
                                                      16384, 256, 256, 0);
    }
    k_norm<<<NINST, 256, 0, stream>>>(points1, xbuf, 129);
    k_sample<<<dim3(NINST, 129), 256, 0, stream>>>(feat, points1, ct_img, xbuf, 129);
    for (int c = 0; c < 4; ++c) {
        int row0 = c * 128 * 129;
        k_gemm_mfma<<<dim3(129, 6), 256, 0, stream>>>(xbuf + (size_t)row0 * 256, wqT1,
                                                      c1_bqkv, 768, scratch,
                                                      16512, 768, 256, 0);
        k_attn<<<dim3(128, 8), 192, 0, stream>>>(scratch, xbuf, 129, c * 128);
        k_head1<<<4128, 256, 0, stream>>>(xbuf, W2_1, b2_1, points1, coarse, out1, row0);
    }

    // ---- stage 2: feat2 recomputed into same buffer ----
    for (int b = 0; b < BIMG; ++b) {
        k_conv_mfma<<<dim3(128, 2), 256, 0, stream>>>(cnn, wb1b, f2_b1, relu_buf, b);
        k_gemm_mfma<<<dim3(128, 2), 256, 0, stream>>>(relu_buf, wb2b, f2_b2, 254,
                                                      feat + (size_t)b * 16384 * 256,
                                                      16384, 256, 256, 0);
    }
    k_norm<<<NINST, 256, 0, stream>>>(coarse, xbuf, 128);
    k_sample<<<dim3(NINST, 128), 256, 0, stream>>>(feat, coarse, ct_img, xbuf, 128);
    for (int c = 0; c < 4; ++c) {
        int row0 = c * 128 * 128;
        k_gemm_mfma<<<dim3(128, 6), 256, 0, stream>>>(xbuf + (size_t)row0 * 256, wqT2,
                                                      c2_bqkv, 768, scratch,
                                                      16384, 768, 256, 0);
        k_attn<<<dim3(128, 8), 128, 0, stream>>>(scratch, xbuf, 128, c * 128);
        k_head2<<<4096, 256, 0, stream>>>(xbuf, W2_2, b2_2, coarse, out2, row0);
    }
}

// Round 5
// 1533.586 us; speedup vs baseline: 2.1493x; 1.2759x over previous
//
#include <hip/hip_runtime.h>
#include <hip/hip_bf16.h>

// ---------------- common helpers ----------------
typedef unsigned short u16;
typedef unsigned int   u32;
typedef float  f32x4 __attribute__((ext_vector_type(4)));
typedef short  s16x8 __attribute__((ext_vector_type(8)));

__device__ __forceinline__ float bf2f(u16 u) {
    return __uint_as_float(((unsigned int)u) << 16);
}
__device__ __forceinline__ u16 f2bf(float f) {
    unsigned int x = __float_as_uint(f);
    unsigned int r = x + 0x7fffu + ((x >> 16) & 1u);
    return (u16)(r >> 16);
}

#define WIMG 128
#define HIMG 128
#define BIMG 8
#define CIN  64
#define NPOINT 128
#define NINST 512

// ---------------- weight conversion (f32 -> bf16, MFMA-friendly layouts) ----------------
// w1 (256 oc, 64 ic, 3, 3) -> wb1[oc][kp*64+ic], kp = ky*3+kx  (Bt layout: N=256 x K=576)
__global__ __launch_bounds__(256) void k_cvt_w1(const float* __restrict__ w,
                                                u16* __restrict__ wb) {
    int idx = blockIdx.x * 256 + threadIdx.x;   // 147456
    int oc = idx / 576, r = idx % 576;
    int kp = r >> 6, ic = r & 63;               // out k-index = kp*64+ic
    wb[idx] = f2bf(w[oc * 576 + ic * 9 + kp]);
}

// w2 (254 oc, 256 ic) -> wb2[oc][ic] bf16, rows oc>=254 zero  (Bt: 256 x 256)
__global__ __launch_bounds__(256) void k_cvt_w2(const float* __restrict__ w,
                                                u16* __restrict__ wb) {
    int idx = blockIdx.x * 256 + threadIdx.x;   // 65536
    int oc = idx >> 8, ic = idx & 255;
    wb[idx] = (oc < 254) ? f2bf(w[oc * 256 + ic]) : (u16)0;
}

// wqkv (256 k, 768 n) -> wqT[n][k] bf16  (Bt: 768 x 256)
__global__ __launch_bounds__(256) void k_cvt_wqkv(const float* __restrict__ w,
                                                  u16* __restrict__ wb) {
    int idx = blockIdx.x * 256 + threadIdx.x;   // 196608
    int n = idx >> 8, k = idx & 255;
    wb[idx] = f2bf(w[k * 768 + n]);
}

// W2 = wo @ whead (256x2), b2 = bo @ whead + bhead (2), all f32
__global__ __launch_bounds__(256) void k_headfuse(const float* __restrict__ wo,
                                                  const float* __restrict__ bo,
                                                  const float* __restrict__ whead,
                                                  const float* __restrict__ bhead,
                                                  float* __restrict__ W2,
                                                  float* __restrict__ b2) {
    int idx = blockIdx.x * 256 + threadIdx.x;   // 512 total
    if (idx < 512) {
        int c = idx >> 1, j = idx & 1;
        float s = 0.f;
        for (int t = 0; t < 256; ++t)
            s = fmaf(wo[c * 256 + t], whead[t * 2 + j], s);
        W2[idx] = s;
    }
    if (idx < 2) {
        float s = bhead[idx];
        for (int t = 0; t < 256; ++t)
            s = fmaf(bo[t], whead[t * 2 + idx], s);
        b2[idx] = s;
    }
}

// ---------------- init polys ----------------
__global__ __launch_bounds__(256) void k_init(const float* __restrict__ whp,
                                              const int* __restrict__ ct_ind,
                                              const int* __restrict__ ct_img,
                                              float* __restrict__ points1,
                                              float* __restrict__ out0) {
    int i = blockIdx.x;
    int t = threadIdx.x;              // t = 2*p + c
    int ind = ct_ind[i];
    int x = ind % WIMG, y = ind / WIMG;
    int b = ct_img[i];
    int p = t >> 1, c = t & 1;
    float off = whp[(((size_t)b * 2 * NPOINT + t) * HIMG + y) * WIMG + x];
    float ctc = (c == 0) ? (float)x : (float)y;
    float ip = off * 10.0f + ctc;
    points1[((size_t)i * 129 + 1 + p) * 2 + c] = ip;
    if (t < 2) points1[(size_t)i * 129 * 2 + t] = (t == 0) ? (float)x : (float)y;
    out0[((size_t)i * NPOINT + p) * 2 + c] = ip * 4.0f;
}

// ---------------- MFMA NT GEMM: C(MxN bf16) = act(A(MxK bf16) @ Bt(NxK bf16)^T + bias) ----
__global__ __launch_bounds__(256) void k_gemm_mfma(const u16* __restrict__ A,
                                                   const u16* __restrict__ Bt,
                                                   const float* __restrict__ bias, int nbias,
                                                   u16* __restrict__ C,
                                                   int M, int N, int K, int relu) {
    __shared__ u16 sA[128 * 40];   // rows padded to 40 elems (80 B, 16B-aligned)
    __shared__ u16 sB[128 * 40];
    int tid = threadIdx.x;
    int wave = tid >> 6, lane = tid & 63;
    int quad = lane >> 4, l16 = lane & 15;
    int m0 = blockIdx.x * 128, n0 = blockIdx.y * 128;
    int wm = (wave >> 1) * 64, wn = (wave & 1) * 64;
    f32x4 acc[4][4];
    #pragma unroll
    for (int a = 0; a < 4; ++a)
        #pragma unroll
        for (int b = 0; b < 4; ++b)
            #pragma unroll
            for (int q = 0; q < 4; ++q) acc[a][b][q] = 0.f;

    for (int kk = 0; kk < K; kk += 32) {
        __syncthreads();
        #pragma unroll
        for (int c = 0; c < 2; ++c) {
            int ch = c * 256 + tid;           // 512 chunks of 16 B
            int row = ch >> 2, sub = ch & 3;
            *(uint4*)&sA[row * 40 + sub * 8] =
                *(const uint4*)&A[(size_t)(m0 + row) * K + kk + sub * 8];
            *(uint4*)&sB[row * 40 + sub * 8] =
                *(const uint4*)&Bt[(size_t)(n0 + row) * K + kk + sub * 8];
        }
        __syncthreads();
        s16x8 aF[4], bF[4];
        #pragma unroll
        for (int mt = 0; mt < 4; ++mt)
            aF[mt] = *(const s16x8*)&sA[(wm + mt * 16 + l16) * 40 + quad * 8];
        #pragma unroll
        for (int nt = 0; nt < 4; ++nt)
            bF[nt] = *(const s16x8*)&sB[(wn + nt * 16 + l16) * 40 + quad * 8];
        #pragma unroll
        for (int mt = 0; mt < 4; ++mt)
            #pragma unroll
            for (int nt = 0; nt < 4; ++nt)
                acc[mt][nt] = __builtin_amdgcn_mfma_f32_16x16x32_bf16(
                    aF[mt], bF[nt], acc[mt][nt], 0, 0, 0);
    }
    #pragma unroll
    for (int nt = 0; nt < 4; ++nt) {
        int col = n0 + wn + nt * 16 + l16;
        float bv = (col < nbias) ? bias[col] : 0.f;
        #pragma unroll
        for (int mt = 0; mt < 4; ++mt) {
            #pragma unroll
            for (int r = 0; r < 4; ++r) {
                int row = m0 + wm + mt * 16 + quad * 4 + r;
                float v = acc[mt][nt][r] + bv;
                if (relu) v = fmaxf(v, 0.f);
                C[(size_t)row * N + col] = f2bf(v);
            }
        }
    }
}

// ---------------- implicit-GEMM 3x3 conv (64->256) + bias + relu, MFMA ----------------
__global__ __launch_bounds__(256) void k_conv_mfma(const float* __restrict__ in,
                                                   const u16* __restrict__ wb1,
                                                   const float* __restrict__ bias,
                                                   u16* __restrict__ out,
                                                   int b) {
    __shared__ u16 sA[128 * 40];
    __shared__ u16 sB[128 * 40];
    int tid = threadIdx.x;
    int wave = tid >> 6, lane = tid & 63;
    int quad = lane >> 4, l16 = lane & 15;
    int y = blockIdx.x;                 // m0 = y*128 (one image row per block)
    int m0 = y * 128;
    int n0 = blockIdx.y * 128;
    int wm = (wave >> 1) * 64, wn = (wave & 1) * 64;
    const float* inb = in + (size_t)b * CIN * HIMG * WIMG;
    f32x4 acc[4][4];
    #pragma unroll
    for (int a = 0; a < 4; ++a)
        #pragma unroll
        for (int c = 0; c < 4; ++c)
            #pragma unroll
            for (int q = 0; q < 4; ++q) acc[a][c][q] = 0.f;

    for (int kk = 0; kk < 576; kk += 32) {
        int kp = kk >> 6;               // kernel position 0..8
        int ic0 = kk & 63;              // 0 or 32
        int ky = kp / 3, kx = kp % 3;
        int iy = y + ky - 1;
        bool vy = (iy >= 0) && (iy < HIMG);
        __syncthreads();
        #pragma unroll
        for (int c = 0; c < 2; ++c) {
            int ch = c * 256 + tid;
            int row = ch >> 2, sub = ch & 3;
            *(uint4*)&sB[row * 40 + sub * 8] =
                *(const uint4*)&wb1[(size_t)(n0 + row) * 576 + kk + sub * 8];
        }
        #pragma unroll
        for (int j = 0; j < 16; ++j) {
            int e = j * 256 + tid;        // 4096 elems
            int row = e & 127, kidx = e >> 7;
            int ix = row + kx - 1;
            float v = 0.f;
            if (vy && ix >= 0 && ix < WIMG)
                v = inb[(size_t)(ic0 + kidx) * (HIMG * WIMG) + iy * WIMG + ix];
            sA[row * 40 + kidx] = f2bf(v);
        }
        __syncthreads();
        s16x8 aF[4], bF[4];
        #pragma unroll
        for (int mt = 0; mt < 4; ++mt)
            aF[mt] = *(const s16x8*)&sA[(wm + mt * 16 + l16) * 40 + quad * 8];
        #pragma unroll
        for (int nt = 0; nt < 4; ++nt)
            bF[nt] = *(const s16x8*)&sB[(wn + nt * 16 + l16) * 40 + quad * 8];
        #pragma unroll
        for (int mt = 0; mt < 4; ++mt)
            #pragma unroll
            for (int nt = 0; nt < 4; ++nt)
                acc[mt][nt] = __builtin_amdgcn_mfma_f32_16x16x32_bf16(
                    aF[mt], bF[nt], acc[mt][nt], 0, 0, 0);
    }
    #pragma unroll
    for (int nt = 0; nt < 4; ++nt) {
        int col = n0 + wn + nt * 16 + l16;
        float bv = bias[col];
        #pragma unroll
        for (int mt = 0; mt < 4; ++mt) {
            #pragma unroll
            for (int r = 0; r < 4; ++r) {
                int row = m0 + wm + mt * 16 + quad * 4 + r;
                float v = fmaxf(acc[mt][nt][r] + bv, 0.f);
                out[(size_t)row * 256 + col] = f2bf(v);
            }
        }
    }
}

// ---------------- normalize_poly -> x[...,254:256] (bf16) ----------------
__global__ __launch_bounds__(256) void k_norm(const float* __restrict__ pts,
                                              u16* __restrict__ xout, int P) {
    int i = blockIdx.x, t = threadIdx.x;
    __shared__ float sx[256], sy[256];
    float px = 0.f, py = 0.f;
    if (t < P) {
        px = pts[((size_t)i * P + t) * 2 + 0];
        py = pts[((size_t)i * P + t) * 2 + 1];
    }
    sx[t] = px; sy[t] = py;
    __syncthreads();
    for (int s = 128; s > 0; s >>= 1) {
        if (t < s) { sx[t] += sx[t + s]; sy[t] += sy[t + s]; }
        __syncthreads();
    }
    float mx = sx[0] / (float)P, my = sy[0] / (float)P;
    __syncthreads();
    float ax = 0.f;
    if (t < P) ax = fmaxf(fabsf(px - mx), fabsf(py - my));
    sx[t] = ax;
    __syncthreads();
    for (int s = 128; s > 0; s >>= 1) {
        if (t < s) sx[t] = fmaxf(sx[t], sx[t + s]);
        __syncthreads();
    }
    float scale = sx[0] + 1e-6f;
    if (t < P) {
        size_t base = ((size_t)i * P + t) * 256;
        xout[base + 254] = f2bf((px - mx) / scale);
        xout[base + 255] = f2bf((py - my) / scale);
    }
}

// ---------------- bilinear sample (pixel-major bf16 feat, 254 ch) -> x[...,0:254] bf16
__global__ __launch_bounds__(256) void k_sample(const u16* __restrict__ feat,
                                                const float* __restrict__ pts,
                                                const int* __restrict__ ct_img,
                                                u16* __restrict__ xout, int P) {
    int i = blockIdx.x, p = blockIdx.y, c = threadIdx.x;
    if (c >= 254) return;
    float px = pts[((size_t)i * P + p) * 2 + 0];
    float py = pts[((size_t)i * P + p) * 2 + 1];
    int b = ct_img[i];
    float ix = px - 0.5f, iy = py - 0.5f;
    float x0f = floorf(ix), y0f = floorf(iy);
    float wx = ix - x0f, wy = iy - y0f;
    int x0 = (int)x0f, y0 = (int)y0f;
    float acc = 0.f;
    #pragma unroll
    for (int dy = 0; dy < 2; ++dy) {
        #pragma unroll
        for (int dx = 0; dx < 2; ++dx) {
            int xx = x0 + dx, yy = y0 + dy;
            float w = (dx ? wx : 1.f - wx) * (dy ? wy : 1.f - wy);
            if (xx >= 0 && xx < WIMG && yy >= 0 && yy < HIMG) {
                acc = fmaf(w, bf2f(feat[(((size_t)b * HIMG + yy) * WIMG + xx) * 256 + c]), acc);
            }
        }
    }
    xout[((size_t)i * P + p) * 256 + c] = f2bf(acc);
}

// ---------------- MFMA attention ----------------
// One block per (inst-in-chunk, head), 4 waves. Computes S^T = K@Q^T (so softmax over k is
// in-lane + shfl_xor over quads), then O^T = V^T @ P^T where lane P-registers directly form
// the B-fragment (V^T staged with compensating k-permutation). No transposes anywhere.
__global__ __launch_bounds__(256) void k_attn_mfma(const u16* __restrict__ qkv, // (chunk*P,768)
                                                   u16* __restrict__ obuf,      // global rows, 256 cols
                                                   int P, int i0) {
    // LDS: Q 144x40, K 144x40, VT 32x168 (all bf16, padded strides for bank spread)
    __shared__ u16 smem[144 * 40 * 2 + 32 * 168];
    u16* sQ = smem;                     // stride 40
    u16* sK = smem + 144 * 40;          // stride 40
    u16* sVT = smem + 2 * 144 * 40;     // stride 168

    int il = blockIdx.x, h = blockIdx.y;
    int ig = i0 + il;
    int tid = threadIdx.x;
    int wave = tid >> 6, lane = tid & 63;
    int quad = lane >> 4, l16 = lane & 15;

    // zero-init (pads must be 0)
    {
        u32* z = (u32*)smem;
        for (int i = tid; i < (144 * 40 * 2 + 32 * 168) / 2; i += 256) z[i] = 0u;
    }
    __syncthreads();
    // stage Q,K rows and V^T (permuted k columns)
    for (int idx = tid; idx < 129 * 16 && (idx >> 4) < P; idx += 256) {
        int row = idx >> 4, c2 = idx & 15;      // c2: which u32 (2 bf16) of 32 cols
        size_t gb = ((size_t)il * P + row) * 768 + h * 32 + c2 * 2;
        *(u32*)&sQ[row * 40 + c2 * 2] = *(const u32*)&qkv[gb];
        *(u32*)&sK[row * 40 + c2 * 2] = *(const u32*)&qkv[gb + 256];
        u32 v = *(const u32*)&qkv[gb + 512];
        int kin = row & 31;
        int pcol = (row & ~31) + ((kin >> 2) & 3) * 8 + (kin >> 4) * 4 + (kin & 3);
        int d0 = c2 * 2;
        sVT[d0 * 168 + pcol] = (u16)(v & 0xffffu);
        sVT[(d0 + 1) * 168 + pcol] = (u16)(v >> 16);
    }
    __syncthreads();

    const float scale = 0.17677669529663689f;
    for (int qt = wave; qt < 9; qt += 4) {
        // B-frag: Q tile (n = q = l16)
        s16x8 bq = *(const s16x8*)&sQ[(qt * 16 + l16) * 40 + quad * 8];
        // S^T tiles: rows k (m), cols q (n)
        f32x4 s4[9];
        #pragma unroll
        for (int kt = 0; kt < 9; ++kt) {
            s16x8 aK = *(const s16x8*)&sK[(kt * 16 + l16) * 40 + quad * 8];
            f32x4 zz = {0.f, 0.f, 0.f, 0.f};
            s4[kt] = __builtin_amdgcn_mfma_f32_16x16x32_bf16(aK, bq, zz, 0, 0, 0);
        }
        // softmax over k (lane holds q = l16; k = kt*16 + quad*4 + r)
        float mx = -1e30f;
        #pragma unroll
        for (int kt = 0; kt < 9; ++kt)
            #pragma unroll
            for (int r = 0; r < 4; ++r) {
                int k = kt * 16 + quad * 4 + r;
                float v = (k < P) ? s4[kt][r] * scale : -1e30f;
                s4[kt][r] = v;
                mx = fmaxf(mx, v);
            }
        mx = fmaxf(mx, __shfl_xor(mx, 16));
        mx = fmaxf(mx, __shfl_xor(mx, 32));
        float l = 0.f;
        #pragma unroll
        for (int kt = 0; kt < 9; ++kt)
            #pragma unroll
            for (int r = 0; r < 4; ++r) {
                float e = __expf(s4[kt][r] - mx);
                s4[kt][r] = e;
                l += e;
            }
        l += __shfl_xor(l, 16);
        l += __shfl_xor(l, 32);
        // P -> bf16
        u16 pb[9][4];
        #pragma unroll
        for (int kt = 0; kt < 9; ++kt)
            #pragma unroll
            for (int r = 0; r < 4; ++r) pb[kt][r] = f2bf(s4[kt][r]);
        // O^T = V^T @ P^T : 5 k-blocks of 32, 2 d-tiles
        f32x4 o[2];
        #pragma unroll
        for (int mt = 0; mt < 2; ++mt)
            #pragma unroll
            for (int q = 0; q < 4; ++q) o[mt][q] = 0.f;
        #pragma unroll
        for (int t = 0; t < 5; ++t) {
            s16x8 bp;
            #pragma unroll
            for (int j = 0; j < 4; ++j) bp[j] = (short)pb[2 * t][j];
            #pragma unroll
            for (int j = 0; j < 4; ++j)
                bp[4 + j] = (2 * t + 1 < 9) ? (short)pb[2 * t + 1][j] : (short)0;
            #pragma unroll
            for (int mt = 0; mt < 2; ++mt) {
                s16x8 aV = *(const s16x8*)&sVT[(mt * 16 + l16) * 168 + t * 32 + quad * 8];
                o[mt] = __builtin_amdgcn_mfma_f32_16x16x32_bf16(aV, bp, o[mt], 0, 0, 0);
            }
        }
        // store: lane holds q = l16 (col), d = mt*16 + quad*4 + r (row)
        int q = qt * 16 + l16;
        if (q < P) {
            float inv = 1.f / l;
            size_t ob = ((size_t)ig * P + q) * 256 + h * 32;
            #pragma unroll
            for (int mt = 0; mt < 2; ++mt) {
                ushort4 st;
                st.x = f2bf(o[mt][0] * inv);
                st.y = f2bf(o[mt][1] * inv);
                st.z = f2bf(o[mt][2] * inv);
                st.w = f2bf(o[mt][3] * inv);
                *(ushort4*)&obuf[ob + mt * 16 + quad * 4] = st;
            }
        }
    }
}

// ---------------- head projection + poly update ----------------
__global__ __launch_bounds__(256) void k_head1(const u16* __restrict__ obuf,
                                               const float* __restrict__ W2,
                                               const float* __restrict__ b2,
                                               const float* __restrict__ pts1,
                                               float* __restrict__ coarse,
                                               float* __restrict__ out1,
                                               int row0) {
    int wave = threadIdx.x >> 6, lane = threadIdx.x & 63;
    int m = row0 + blockIdx.x * 4 + wave;
    const u16* orow = obuf + (size_t)m * 256;
    ushort4 u = *(const ushort4*)(orow + lane * 4);
    float4 w0 = *(const float4*)(W2 + lane * 8);
    float4 w1 = *(const float4*)(W2 + lane * 8 + 4);
    float c0 = bf2f(u.x), c1 = bf2f(u.y), c2 = bf2f(u.z), c3 = bf2f(u.w);
    float s0 = c0 * w0.x + c1 * w0.z + c2 * w1.x + c3 * w1.z;
    float s1 = c0 * w0.y + c1 * w0.w + c2 * w1.y + c3 * w1.w;
    for (int off = 32; off > 0; off >>= 1) {
        s0 += __shfl_down(s0, off);
        s1 += __shfl_down(s1, off);
    }
    if (lane == 0) {
        int i = m / 129, p = m % 129;
        if (p > 0) {
            float o0 = s0 + b2[0], o1 = s1 + b2[1];
            float i0 = pts1[(size_t)m * 2 + 0];
            float i1 = pts1[(size_t)m * 2 + 1];
            float cc0 = o0 * 4.f + i0, cc1 = o1 * 4.f + i1;
            size_t cm = (size_t)i * 128 + (p - 1);
            coarse[cm * 2 + 0] = cc0;
            coarse[cm * 2 + 1] = cc1;
            out1[cm * 2 + 0] = cc0 * 4.f;
            out1[cm * 2 + 1] = cc1 * 4.f;
        }
    }
}

__global__ __launch_bounds__(256) void k_head2(const u16* __restrict__ obuf,
                                               const float* __restrict__ W2,
                                               const float* __restrict__ b2,
                                               const float* __restrict__ coarse,
                                               float* __restrict__ out2,
                                               int row0) {
    int wave = threadIdx.x >> 6, lane = threadIdx.x & 63;
    int m = row0 + blockIdx.x * 4 + wave;
    const u16* orow = obuf + (size_t)m * 256;
    ushort4 u = *(const ushort4*)(orow + lane * 4);
    float4 w0 = *(const float4*)(W2 + lane * 8);
    float4 w1 = *(const float4*)(W2 + lane * 8 + 4);
    float c0 = bf2f(u.x), c1 = bf2f(u.y), c2 = bf2f(u.z), c3 = bf2f(u.w);
    float s0 = c0 * w0.x + c1 * w0.z + c2 * w1.x + c3 * w1.z;
    float s1 = c0 * w0.y + c1 * w0.w + c2 * w1.y + c3 * w1.w;
    for (int off = 32; off > 0; off >>= 1) {
        s0 += __shfl_down(s0, off);
        s1 += __shfl_down(s1, off);
    }
    if (lane == 0) {
        float f0 = s0 + b2[0] + coarse[(size_t)m * 2 + 0];
        float f1 = s1 + b2[1] + coarse[(size_t)m * 2 + 1];
        out2[(size_t)m * 2 + 0] = f0 * 4.f;
        out2[(size_t)m * 2 + 1] = f1 * 4.f;
    }
}

// ---------------- host ----------------
extern "C" void kernel_launch(void* const* d_in, const int* in_sizes, int n_in,
                              void* d_out, int out_size, void* d_ws, size_t ws_size,
                              hipStream_t stream) {
    const float* cnn     = (const float*)d_in[0];
    const float* whp     = (const float*)d_in[1];
    const int*   ct_ind  = (const int*)d_in[2];
    const int*   ct_img  = (const int*)d_in[3];
    const float* f1_w1   = (const float*)d_in[4];
    const float* f1_b1   = (const float*)d_in[5];
    const float* f1_w2   = (const float*)d_in[6];
    const float* f1_b2   = (const float*)d_in[7];
    const float* f2_w1   = (const float*)d_in[8];
    const float* f2_b1   = (const float*)d_in[9];
    const float* f2_w2   = (const float*)d_in[10];
    const float* f2_b2   = (const float*)d_in[11];
    const float* c1_wqkv = (const float*)d_in[12];
    const float* c1_bqkv = (const float*)d_in[13];
    const float* c1_wo   = (const float*)d_in[14];
    const float* c1_bo   = (const float*)d_in[15];
    const float* c1_wh   = (const float*)d_in[16];
    const float* c1_bh   = (const float*)d_in[17];
    const float* c2_wqkv = (const float*)d_in[18];
    const float* c2_bqkv = (const float*)d_in[19];
    const float* c2_wo   = (const float*)d_in[20];
    const float* c2_bo   = (const float*)d_in[21];
    const float* c2_wh   = (const float*)d_in[22];
    const float* c2_bh   = (const float*)d_in[23];

    // ws layout, total ~129.0 MB (round-3/4 PASS proves this budget fits)
    char* ws = (char*)d_ws;
    float* points1 = (float*)(ws + 0);                // 512*129*2 f32   (528384 B)
    float* coarse  = (float*)(ws + 528384);           // 512*128*2 f32
    float* W2_1    = (float*)(ws + 1052672);          // 512 f32
    float* b2_1    = (float*)(ws + 1054720);
    float* W2_2    = (float*)(ws + 1054976);
    float* b2_2    = (float*)(ws + 1057024);
    u16*   wb1a    = (u16*)(ws + 1057280);            // 256x576 bf16 (294912 B)
    u16*   wb1b    = (u16*)(ws + 1352192);
    u16*   wb2a    = (u16*)(ws + 1647104);            // 256x256 bf16 (131072 B)
    u16*   wb2b    = (u16*)(ws + 1778176);
    u16*   wqT1    = (u16*)(ws + 1909248);            // 768x256 bf16 (393216 B)
    u16*   wqT2    = (u16*)(ws + 2302464);
    u16*   feat    = (u16*)(ws + 2695680);            // 8*16384*256 bf16 (67108864 B)
    u16*   xbuf    = (u16*)(ws + 69804544);           // 66048*256 bf16 (33816576 B); relu_buf alias
    u16*   scratch = (u16*)(ws + 103621120);          // qkv chunk 16512*768 bf16 (25362432 B)
    // end: 128983552 B

    u16* relu_buf = xbuf;   // alias: conv phases never overlap attention phases

    float* out0 = (float*)d_out;
    float* out1 = out0 + 131072;
    float* out2 = out0 + 262144;

    // prep
    k_cvt_w1<<<576, 256, 0, stream>>>(f1_w1, wb1a);
    k_cvt_w1<<<576, 256, 0, stream>>>(f2_w1, wb1b);
    k_cvt_w2<<<256, 256, 0, stream>>>(f1_w2, wb2a);
    k_cvt_w2<<<256, 256, 0, stream>>>(f2_w2, wb2b);
    k_cvt_wqkv<<<768, 256, 0, stream>>>(c1_wqkv, wqT1);
    k_cvt_wqkv<<<768, 256, 0, stream>>>(c2_wqkv, wqT2);
    k_headfuse<<<2, 256, 0, stream>>>(c1_wo, c1_bo, c1_wh, c1_bh, W2_1, b2_1);
    k_headfuse<<<2, 256, 0, stream>>>(c2_wo, c2_bo, c2_wh, c2_bh, W2_2, b2_2);

    k_init<<<NINST, 256, 0, stream>>>(whp, ct_ind, ct_img, points1, out0);

    // ---- stage 1: feat1 = conv3x3(relu) -> 1x1 ----
    for (int b = 0; b < BIMG; ++b) {
        k_conv_mfma<<<dim3(128, 2), 256, 0, stream>>>(cnn, wb1a, f1_b1, relu_buf, b);
        k_gemm_mfma<<<dim3(128, 2), 256, 0, stream>>>(relu_buf, wb2a, f1_b2, 254,
                                                      feat + (size_t)b * 16384 * 256,
                                                      16384, 256, 256, 0);
    }
    k_norm<<<NINST, 256, 0, stream>>>(points1, xbuf, 129);
    k_sample<<<dim3(NINST, 129), 256, 0, stream>>>(feat, points1, ct_img, xbuf, 129);
    for (int c = 0; c < 4; ++c) {
        int row0 = c * 128 * 129;
        k_gemm_mfma<<<dim3(129, 6), 256, 0, stream>>>(xbuf + (size_t)row0 * 256, wqT1,
                                                      c1_bqkv, 768, scratch,
                                                      16512, 768, 256, 0);
        k_attn_mfma<<<dim3(128, 8), 256, 0, stream>>>(scratch, xbuf, 129, c * 128);
        k_head1<<<4128, 256, 0, stream>>>(xbuf, W2_1, b2_1, points1, coarse, out1, row0);
    }

    // ---- stage 2: feat2 recomputed into same buffer ----
    for (int b = 0; b < BIMG; ++b) {
        k_conv_mfma<<<dim3(128, 2), 256, 0, stream>>>(cnn, wb1b, f2_b1, relu_buf, b);
        k_gemm_mfma<<<dim3(128, 2), 256, 0, stream>>>(relu_buf, wb2b, f2_b2, 254,
                                                      feat + (size_t)b * 16384 * 256,
                                                      16384, 256, 256, 0);
    }
    k_norm<<<NINST, 256, 0, stream>>>(coarse, xbuf, 128);
    k_sample<<<dim3(NINST, 128), 256, 0, stream>>>(feat, coarse, ct_img, xbuf, 128);
    for (int c = 0; c < 4; ++c) {
        int row0 = c * 128 * 128;
        k_gemm_mfma<<<dim3(128, 6), 256, 0, stream>>>(xbuf + (size_t)row0 * 256, wqT2,
                                                      c2_bqkv, 768, scratch,
                                                      16384, 768, 256, 0);
        k_attn_mfma<<<dim3(128, 8), 256, 0, stream>>>(scratch, xbuf, 128, c * 128);
        k_head2<<<4096, 256, 0, stream>>>(xbuf, W2_2, b2_2, coarse, out2, row0);
    }
}

// Round 6
// 884.448 us; speedup vs baseline: 3.7268x; 1.7339x over previous
//
#include <hip/hip_runtime.h>
#include <hip/hip_bf16.h>

// ---------------- common helpers ----------------
typedef unsigned short u16;
typedef unsigned int   u32;
typedef float  f32x4 __attribute__((ext_vector_type(4)));
typedef short  s16x8 __attribute__((ext_vector_type(8)));

__device__ __forceinline__ float bf2f(u16 u) {
    return __uint_as_float(((unsigned int)u) << 16);
}
__device__ __forceinline__ u16 f2bf(float f) {
    unsigned int x = __float_as_uint(f);
    unsigned int r = x + 0x7fffu + ((x >> 16) & 1u);
    return (u16)(r >> 16);
}

#define WIMG 128
#define HIMG 128
#define BIMG 8
#define CIN  64
#define NPOINT 128
#define NINST 512

// ---------------- weight conversion (f32 -> bf16, MFMA-friendly layouts) ----------------
// w1 (256 oc, 64 ic, 3, 3) -> wb1[oc][kp*64+ic], kp = ky*3+kx  (Bt layout: N=256 x K=576)
__global__ __launch_bounds__(256) void k_cvt_w1(const float* __restrict__ w,
                                                u16* __restrict__ wb) {
    int idx = blockIdx.x * 256 + threadIdx.x;   // 147456
    int oc = idx / 576, r = idx % 576;
    int kp = r >> 6, ic = r & 63;
    wb[idx] = f2bf(w[oc * 576 + ic * 9 + kp]);
}

// w2 (254 oc, 256 ic) -> wb2[oc][ic] bf16, rows oc>=254 zero  (Bt: 256 x 256)
__global__ __launch_bounds__(256) void k_cvt_w2(const float* __restrict__ w,
                                                u16* __restrict__ wb) {
    int idx = blockIdx.x * 256 + threadIdx.x;   // 65536
    int oc = idx >> 8, ic = idx & 255;
    wb[idx] = (oc < 254) ? f2bf(w[oc * 256 + ic]) : (u16)0;
}

// wqkv (256 k, 768 n) -> wqT[n][k] bf16  (Bt: 768 x 256)
__global__ __launch_bounds__(256) void k_cvt_wqkv(const float* __restrict__ w,
                                                  u16* __restrict__ wb) {
    int idx = blockIdx.x * 256 + threadIdx.x;   // 196608
    int n = idx >> 8, k = idx & 255;
    wb[idx] = f2bf(w[k * 768 + n]);
}

// W2 = wo @ whead (256x2), b2 = bo @ whead + bhead (2), all f32
__global__ __launch_bounds__(256) void k_headfuse(const float* __restrict__ wo,
                                                  const float* __restrict__ bo,
                                                  const float* __restrict__ whead,
                                                  const float* __restrict__ bhead,
                                                  float* __restrict__ W2,
                                                  float* __restrict__ b2) {
    int idx = blockIdx.x * 256 + threadIdx.x;   // 512 total
    if (idx < 512) {
        int c = idx >> 1, j = idx & 1;
        float s = 0.f;
        for (int t = 0; t < 256; ++t)
            s = fmaf(wo[c * 256 + t], whead[t * 2 + j], s);
        W2[idx] = s;
    }
    if (idx < 2) {
        float s = bhead[idx];
        for (int t = 0; t < 256; ++t)
            s = fmaf(bo[t], whead[t * 2 + idx], s);
        b2[idx] = s;
    }
}

// ---------------- NCHW f32 (8,64,128,128) -> NHWC bf16 (8,128,128,64) ----------------
// grid 1024 = (b,y); LDS tile transpose, coalesced both sides.
__global__ __launch_bounds__(256) void k_nhwc(const float* __restrict__ in,
                                              u16* __restrict__ out) {
    __shared__ u16 sT[128][80];   // [x][ic], stride 80 u16 = 160 B (16B-aligned rows)
    int b = blockIdx.x >> 7, y = blockIdx.x & 127;
    int tid = threadIdx.x;
    const float* ib = in + ((size_t)b * CIN * HIMG + y) * WIMG;
    int x4 = tid & 31, icg = tid >> 5;     // 32 float4 spans x, 8 ic per pass
    #pragma unroll
    for (int pass = 0; pass < 8; ++pass) {
        int ic = pass * 8 + icg;
        float4 v = *(const float4*)&ib[(size_t)ic * (HIMG * WIMG) + x4 * 4];
        sT[x4 * 4 + 0][ic] = f2bf(v.x);
        sT[x4 * 4 + 1][ic] = f2bf(v.y);
        sT[x4 * 4 + 2][ic] = f2bf(v.z);
        sT[x4 * 4 + 3][ic] = f2bf(v.w);
    }
    __syncthreads();
    u16* ob = out + ((size_t)b * HIMG + y) * WIMG * 64;
    int icu = tid & 7, xw = tid >> 3;      // 8 uint4 per x-row, 32 x per pass
    #pragma unroll
    for (int pass = 0; pass < 4; ++pass) {
        int x = pass * 32 + xw;
        uint4 v = *(const uint4*)&sT[x][icu * 8];
        *(uint4*)&ob[(size_t)x * 64 + icu * 8] = v;
    }
}

// ---------------- init polys ----------------
__global__ __launch_bounds__(256) void k_init(const float* __restrict__ whp,
                                              const int* __restrict__ ct_ind,
                                              const int* __restrict__ ct_img,
                                              float* __restrict__ points1,
                                              float* __restrict__ out0) {
    int i = blockIdx.x;
    int t = threadIdx.x;              // t = 2*p + c
    int ind = ct_ind[i];
    int x = ind % WIMG, y = ind / WIMG;
    int b = ct_img[i];
    int p = t >> 1, c = t & 1;
    float off = whp[(((size_t)b * 2 * NPOINT + t) * HIMG + y) * WIMG + x];
    float ctc = (c == 0) ? (float)x : (float)y;
    float ip = off * 10.0f + ctc;
    points1[((size_t)i * 129 + 1 + p) * 2 + c] = ip;
    if (t < 2) points1[(size_t)i * 129 * 2 + t] = (t == 0) ? (float)x : (float)y;
    out0[((size_t)i * NPOINT + p) * 2 + c] = ip * 4.0f;
}

// ---------------- MFMA NT GEMM: C(MxN bf16) = act(A(MxK bf16) @ Bt(NxK bf16)^T + bias) ----
__global__ __launch_bounds__(256) void k_gemm_mfma(const u16* __restrict__ A,
                                                   const u16* __restrict__ Bt,
                                                   const float* __restrict__ bias, int nbias,
                                                   u16* __restrict__ C,
                                                   int M, int N, int K, int relu) {
    __shared__ u16 sA[128 * 40];
    __shared__ u16 sB[128 * 40];
    int tid = threadIdx.x;
    int wave = tid >> 6, lane = tid & 63;
    int quad = lane >> 4, l16 = lane & 15;
    int m0 = blockIdx.x * 128, n0 = blockIdx.y * 128;
    int wm = (wave >> 1) * 64, wn = (wave & 1) * 64;
    f32x4 acc[4][4];
    #pragma unroll
    for (int a = 0; a < 4; ++a)
        #pragma unroll
        for (int b = 0; b < 4; ++b)
            #pragma unroll
            for (int q = 0; q < 4; ++q) acc[a][b][q] = 0.f;

    for (int kk = 0; kk < K; kk += 32) {
        __syncthreads();
        #pragma unroll
        for (int c = 0; c < 2; ++c) {
            int ch = c * 256 + tid;
            int row = ch >> 2, sub = ch & 3;
            *(uint4*)&sA[row * 40 + sub * 8] =
                *(const uint4*)&A[(size_t)(m0 + row) * K + kk + sub * 8];
            *(uint4*)&sB[row * 40 + sub * 8] =
                *(const uint4*)&Bt[(size_t)(n0 + row) * K + kk + sub * 8];
        }
        __syncthreads();
        s16x8 aF[4], bF[4];
        #pragma unroll
        for (int mt = 0; mt < 4; ++mt)
            aF[mt] = *(const s16x8*)&sA[(wm + mt * 16 + l16) * 40 + quad * 8];
        #pragma unroll
        for (int nt = 0; nt < 4; ++nt)
            bF[nt] = *(const s16x8*)&sB[(wn + nt * 16 + l16) * 40 + quad * 8];
        #pragma unroll
        for (int mt = 0; mt < 4; ++mt)
            #pragma unroll
            for (int nt = 0; nt < 4; ++nt)
                acc[mt][nt] = __builtin_amdgcn_mfma_f32_16x16x32_bf16(
                    aF[mt], bF[nt], acc[mt][nt], 0, 0, 0);
    }
    #pragma unroll
    for (int nt = 0; nt < 4; ++nt) {
        int col = n0 + wn + nt * 16 + l16;
        float bv = (col < nbias) ? bias[col] : 0.f;
        #pragma unroll
        for (int mt = 0; mt < 4; ++mt) {
            #pragma unroll
            for (int r = 0; r < 4; ++r) {
                int row = m0 + wm + mt * 16 + quad * 4 + r;
                float v = acc[mt][nt][r] + bv;
                if (relu) v = fmaxf(v, 0.f);
                C[(size_t)row * N + col] = f2bf(v);
            }
        }
    }
}

// ---------------- implicit-GEMM 3x3 conv (64->256) + bias + relu, MFMA, all images ------
// inT NHWC bf16 (8,128,128,64); wb1 Bt (256 oc x 576 k), k=(ky*3+kx)*64+ic.
// out (8*16384 px, 256 oc) bf16. grid (128 y, 2 ocg, 8 b), block 256.
__global__ __launch_bounds__(256) void k_conv_mfma(const u16* __restrict__ inT,
                                                   const u16* __restrict__ wb1,
                                                   const float* __restrict__ bias,
                                                   u16* __restrict__ out) {
    __shared__ u16 sA[128 * 40];
    __shared__ u16 sB[128 * 40];
    int tid = threadIdx.x;
    int wave = tid >> 6, lane = tid & 63;
    int quad = lane >> 4, l16 = lane & 15;
    int y = blockIdx.x;
    int n0 = blockIdx.y * 128;
    int b = blockIdx.z;
    int wm = (wave >> 1) * 64, wn = (wave & 1) * 64;
    const u16* inb = inT + (size_t)b * HIMG * WIMG * 64;
    f32x4 acc[4][4];
    #pragma unroll
    for (int a = 0; a < 4; ++a)
        #pragma unroll
        for (int c = 0; c < 4; ++c)
            #pragma unroll
            for (int q = 0; q < 4; ++q) acc[a][c][q] = 0.f;

    for (int kk = 0; kk < 576; kk += 32) {
        int kp = kk >> 6;               // kernel position 0..8
        int ic0 = kk & 63;              // 0 or 32
        int ky = kp / 3, kx = kp % 3;
        int iy = y + ky - 1;
        bool vy = (iy >= 0) && (iy < HIMG);
        __syncthreads();
        #pragma unroll
        for (int c = 0; c < 2; ++c) {
            int ch = c * 256 + tid;
            int row = ch >> 2, sub = ch & 3;
            // B tile (128 oc x 32 k)
            *(uint4*)&sB[row * 40 + sub * 8] =
                *(const uint4*)&wb1[(size_t)(n0 + row) * 576 + kk + sub * 8];
            // A tile (128 px x 32 ic) from NHWC bf16, shifted window
            int ix = row + kx - 1;
            uint4 v = make_uint4(0u, 0u, 0u, 0u);
            if (vy && ix >= 0 && ix < WIMG)
                v = *(const uint4*)&inb[((size_t)iy * WIMG + ix) * 64 + ic0 + sub * 8];
            *(uint4*)&sA[row * 40 + sub * 8] = v;
        }
        __syncthreads();
        s16x8 aF[4], bF[4];
        #pragma unroll
        for (int mt = 0; mt < 4; ++mt)
            aF[mt] = *(const s16x8*)&sA[(wm + mt * 16 + l16) * 40 + quad * 8];
        #pragma unroll
        for (int nt = 0; nt < 4; ++nt)
            bF[nt] = *(const s16x8*)&sB[(wn + nt * 16 + l16) * 40 + quad * 8];
        #pragma unroll
        for (int mt = 0; mt < 4; ++mt)
            #pragma unroll
            for (int nt = 0; nt < 4; ++nt)
                acc[mt][nt] = __builtin_amdgcn_mfma_f32_16x16x32_bf16(
                    aF[mt], bF[nt], acc[mt][nt], 0, 0, 0);
    }
    u16* outb = out + (size_t)b * (HIMG * WIMG) * 256;
    #pragma unroll
    for (int nt = 0; nt < 4; ++nt) {
        int col = n0 + wn + nt * 16 + l16;
        float bv = bias[col];
        #pragma unroll
        for (int mt = 0; mt < 4; ++mt) {
            #pragma unroll
            for (int r = 0; r < 4; ++r) {
                int row = y * 128 + wm + mt * 16 + quad * 4 + r;
                float v = fmaxf(acc[mt][nt][r] + bv, 0.f);
                outb[(size_t)row * 256 + col] = f2bf(v);
            }
        }
    }
}

// ---------------- normalize_poly -> x[...,254:256] (bf16) ----------------
__global__ __launch_bounds__(256) void k_norm(const float* __restrict__ pts,
                                              u16* __restrict__ xout, int P) {
    int i = blockIdx.x, t = threadIdx.x;
    __shared__ float sx[256], sy[256];
    float px = 0.f, py = 0.f;
    if (t < P) {
        px = pts[((size_t)i * P + t) * 2 + 0];
        py = pts[((size_t)i * P + t) * 2 + 1];
    }
    sx[t] = px; sy[t] = py;
    __syncthreads();
    for (int s = 128; s > 0; s >>= 1) {
        if (t < s) { sx[t] += sx[t + s]; sy[t] += sy[t + s]; }
        __syncthreads();
    }
    float mx = sx[0] / (float)P, my = sy[0] / (float)P;
    __syncthreads();
    float ax = 0.f;
    if (t < P) ax = fmaxf(fabsf(px - mx), fabsf(py - my));
    sx[t] = ax;
    __syncthreads();
    for (int s = 128; s > 0; s >>= 1) {
        if (t < s) sx[t] = fmaxf(sx[t], sx[t + s]);
        __syncthreads();
    }
    float scale = sx[0] + 1e-6f;
    if (t < P) {
        size_t base = ((size_t)i * P + t) * 256;
        xout[base + 254] = f2bf((px - mx) / scale);
        xout[base + 255] = f2bf((py - my) / scale);
    }
}

// ---------------- bilinear sample: 2 points/block, 2 channels/thread (u32) ----------------
__global__ __launch_bounds__(256) void k_sample(const u16* __restrict__ feat,
                                                const float* __restrict__ pts,
                                                const int* __restrict__ ct_img,
                                                u16* __restrict__ xout, int P) {
    int i = blockIdx.x;
    int p = blockIdx.y * 2 + (threadIdx.x >> 7);
    int c0 = (threadIdx.x & 127) * 2;
    if (p >= P || c0 >= 254) return;
    float px = pts[((size_t)i * P + p) * 2 + 0];
    float py = pts[((size_t)i * P + p) * 2 + 1];
    int b = ct_img[i];
    float ix = px - 0.5f, iy = py - 0.5f;
    float x0f = floorf(ix), y0f = floorf(iy);
    float wx = ix - x0f, wy = iy - y0f;
    int x0 = (int)x0f, y0 = (int)y0f;
    float a0 = 0.f, a1 = 0.f;
    #pragma unroll
    for (int dy = 0; dy < 2; ++dy) {
        #pragma unroll
        for (int dx = 0; dx < 2; ++dx) {
            int xx = x0 + dx, yy = y0 + dy;
            float w = (dx ? wx : 1.f - wx) * (dy ? wy : 1.f - wy);
            if (xx >= 0 && xx < WIMG && yy >= 0 && yy < HIMG) {
                u32 v = *(const u32*)&feat[(((size_t)b * HIMG + yy) * WIMG + xx) * 256 + c0];
                a0 = fmaf(w, bf2f((u16)(v & 0xffffu)), a0);
                a1 = fmaf(w, bf2f((u16)(v >> 16)), a1);
            }
        }
    }
    u32 st = (u32)f2bf(a0) | ((u32)f2bf(a1) << 16);
    *(u32*)&xout[((size_t)i * P + p) * 256 + c0] = st;
}

// ---------------- MFMA attention (S^T = K@Q^T, O^T = V^T@P^T; no transposes) ----------------
__global__ __launch_bounds__(256) void k_attn_mfma(const u16* __restrict__ qkv, // (512*P,768)
                                                   u16* __restrict__ obuf,      // rows, 256 cols
                                                   int P) {
    __shared__ u16 smem[144 * 40 * 2 + 32 * 168];
    u16* sQ = smem;                     // stride 40
    u16* sK = smem + 144 * 40;          // stride 40
    u16* sVT = smem + 2 * 144 * 40;     // stride 168

    int il = blockIdx.x, h = blockIdx.y;
    int tid = threadIdx.x;
    int wave = tid >> 6, lane = tid & 63;
    int quad = lane >> 4, l16 = lane & 15;

    {
        u32* z = (u32*)smem;
        for (int i = tid; i < (144 * 40 * 2 + 32 * 168) / 2; i += 256) z[i] = 0u;
    }
    __syncthreads();
    for (int idx = tid; idx < 129 * 16 && (idx >> 4) < P; idx += 256) {
        int row = idx >> 4, c2 = idx & 15;
        size_t gb = ((size_t)il * P + row) * 768 + h * 32 + c2 * 2;
        *(u32*)&sQ[row * 40 + c2 * 2] = *(const u32*)&qkv[gb];
        *(u32*)&sK[row * 40 + c2 * 2] = *(const u32*)&qkv[gb + 256];
        u32 v = *(const u32*)&qkv[gb + 512];
        int kin = row & 31;
        int pcol = (row & ~31) + ((kin >> 2) & 3) * 8 + (kin >> 4) * 4 + (kin & 3);
        int d0 = c2 * 2;
        sVT[d0 * 168 + pcol] = (u16)(v & 0xffffu);
        sVT[(d0 + 1) * 168 + pcol] = (u16)(v >> 16);
    }
    __syncthreads();

    const float scale = 0.17677669529663689f;
    for (int qt = wave; qt < 9; qt += 4) {
        s16x8 bq = *(const s16x8*)&sQ[(qt * 16 + l16) * 40 + quad * 8];
        f32x4 s4[9];
        #pragma unroll
        for (int kt = 0; kt < 9; ++kt) {
            s16x8 aK = *(const s16x8*)&sK[(kt * 16 + l16) * 40 + quad * 8];
            f32x4 zz = {0.f, 0.f, 0.f, 0.f};
            s4[kt] = __builtin_amdgcn_mfma_f32_16x16x32_bf16(aK, bq, zz, 0, 0, 0);
        }
        float mx = -1e30f;
        #pragma unroll
        for (int kt = 0; kt < 9; ++kt)
            #pragma unroll
            for (int r = 0; r < 4; ++r) {
                int k = kt * 16 + quad * 4 + r;
                float v = (k < P) ? s4[kt][r] * scale : -1e30f;
                s4[kt][r] = v;
                mx = fmaxf(mx, v);
            }
        mx = fmaxf(mx, __shfl_xor(mx, 16));
        mx = fmaxf(mx, __shfl_xor(mx, 32));
        float l = 0.f;
        #pragma unroll
        for (int kt = 0; kt < 9; ++kt)
            #pragma unroll
            for (int r = 0; r < 4; ++r) {
                float e = __expf(s4[kt][r] - mx);
                s4[kt][r] = e;
                l += e;
            }
        l += __shfl_xor(l, 16);
        l += __shfl_xor(l, 32);
        u16 pb[9][4];
        #pragma unroll
        for (int kt = 0; kt < 9; ++kt)
            #pragma unroll
            for (int r = 0; r < 4; ++r) pb[kt][r] = f2bf(s4[kt][r]);
        f32x4 o[2];
        #pragma unroll
        for (int mt = 0; mt < 2; ++mt)
            #pragma unroll
            for (int q = 0; q < 4; ++q) o[mt][q] = 0.f;
        #pragma unroll
        for (int t = 0; t < 5; ++t) {
            s16x8 bp;
            #pragma unroll
            for (int j = 0; j < 4; ++j) bp[j] = (short)pb[2 * t][j];
            #pragma unroll
            for (int j = 0; j < 4; ++j)
                bp[4 + j] = (2 * t + 1 < 9) ? (short)pb[2 * t + 1][j] : (short)0;
            #pragma unroll
            for (int mt = 0; mt < 2; ++mt) {
                s16x8 aV = *(const s16x8*)&sVT[(mt * 16 + l16) * 168 + t * 32 + quad * 8];
                o[mt] = __builtin_amdgcn_mfma_f32_16x16x32_bf16(aV, bp, o[mt], 0, 0, 0);
            }
        }
        int q = qt * 16 + l16;
        if (q < P) {
            float inv = 1.f / l;
            size_t ob = ((size_t)il * P + q) * 256 + h * 32;
            #pragma unroll
            for (int mt = 0; mt < 2; ++mt) {
                ushort4 st;
                st.x = f2bf(o[mt][0] * inv);
                st.y = f2bf(o[mt][1] * inv);
                st.z = f2bf(o[mt][2] * inv);
                st.w = f2bf(o[mt][3] * inv);
                *(ushort4*)&obuf[ob + mt * 16 + quad * 4] = st;
            }
        }
    }
}

// ---------------- head projection + poly update ----------------
__global__ __launch_bounds__(256) void k_head1(const u16* __restrict__ obuf,
                                               const float* __restrict__ W2,
                                               const float* __restrict__ b2,
                                               const float* __restrict__ pts1,
                                               float* __restrict__ coarse,
                                               float* __restrict__ out1) {
    int wave = threadIdx.x >> 6, lane = threadIdx.x & 63;
    int m = blockIdx.x * 4 + wave;
    const u16* orow = obuf + (size_t)m * 256;
    ushort4 u = *(const ushort4*)(orow + lane * 4);
    float4 w0 = *(const float4*)(W2 + lane * 8);
    float4 w1 = *(const float4*)(W2 + lane * 8 + 4);
    float c0 = bf2f(u.x), c1 = bf2f(u.y), c2 = bf2f(u.z), c3 = bf2f(u.w);
    float s0 = c0 * w0.x + c1 * w0.z + c2 * w1.x + c3 * w1.z;
    float s1 = c0 * w0.y + c1 * w0.w + c2 * w1.y + c3 * w1.w;
    for (int off = 32; off > 0; off >>= 1) {
        s0 += __shfl_down(s0, off);
        s1 += __shfl_down(s1, off);
    }
    if (lane == 0) {
        int i = m / 129, p = m % 129;
        if (p > 0) {
            float o0 = s0 + b2[0], o1 = s1 + b2[1];
            float i0 = pts1[(size_t)m * 2 + 0];
            float i1 = pts1[(size_t)m * 2 + 1];
            float cc0 = o0 * 4.f + i0, cc1 = o1 * 4.f + i1;
            size_t cm = (size_t)i * 128 + (p - 1);
            coarse[cm * 2 + 0] = cc0;
            coarse[cm * 2 + 1] = cc1;
            out1[cm * 2 + 0] = cc0 * 4.f;
            out1[cm * 2 + 1] = cc1 * 4.f;
        }
    }
}

__global__ __launch_bounds__(256) void k_head2(const u16* __restrict__ obuf,
                                               const float* __restrict__ W2,
                                               const float* __restrict__ b2,
                                               const float* __restrict__ coarse,
                                               float* __restrict__ out2) {
    int wave = threadIdx.x >> 6, lane = threadIdx.x & 63;
    int m = blockIdx.x * 4 + wave;
    const u16* orow = obuf + (size_t)m * 256;
    ushort4 u = *(const ushort4*)(orow + lane * 4);
    float4 w0 = *(const float4*)(W2 + lane * 8);
    float4 w1 = *(const float4*)(W2 + lane * 8 + 4);
    float c0 = bf2f(u.x), c1 = bf2f(u.y), c2 = bf2f(u.z), c3 = bf2f(u.w);
    float s0 = c0 * w0.x + c1 * w0.z + c2 * w1.x + c3 * w1.z;
    float s1 = c0 * w0.y + c1 * w0.w + c2 * w1.y + c3 * w1.w;
    for (int off = 32; off > 0; off >>= 1) {
        s0 += __shfl_down(s0, off);
        s1 += __shfl_down(s1, off);
    }
    if (lane == 0) {
        float f0 = s0 + b2[0] + coarse[(size_t)m * 2 + 0];
        float f1 = s1 + b2[1] + coarse[(size_t)m * 2 + 1];
        out2[(size_t)m * 2 + 0] = f0 * 4.f;
        out2[(size_t)m * 2 + 1] = f1 * 4.f;
    }
}

// ---------------- host ----------------
extern "C" void kernel_launch(void* const* d_in, const int* in_sizes, int n_in,
                              void* d_out, int out_size, void* d_ws, size_t ws_size,
                              hipStream_t stream) {
    const float* cnn     = (const float*)d_in[0];
    const float* whp     = (const float*)d_in[1];
    const int*   ct_ind  = (const int*)d_in[2];
    const int*   ct_img  = (const int*)d_in[3];
    const float* f1_w1   = (const float*)d_in[4];
    const float* f1_b1   = (const float*)d_in[5];
    const float* f1_w2   = (const float*)d_in[6];
    const float* f1_b2   = (const float*)d_in[7];
    const float* f2_w1   = (const float*)d_in[8];
    const float* f2_b1   = (const float*)d_in[9];
    const float* f2_w2   = (const float*)d_in[10];
    const float* f2_b2   = (const float*)d_in[11];
    const float* c1_wqkv = (const float*)d_in[12];
    const float* c1_bqkv = (const float*)d_in[13];
    const float* c1_wo   = (const float*)d_in[14];
    const float* c1_bo   = (const float*)d_in[15];
    const float* c1_wh   = (const float*)d_in[16];
    const float* c1_bh   = (const float*)d_in[17];
    const float* c2_wqkv = (const float*)d_in[18];
    const float* c2_bqkv = (const float*)d_in[19];
    const float* c2_wo   = (const float*)d_in[20];
    const float* c2_bo   = (const float*)d_in[21];
    const float* c2_wh   = (const float*)d_in[22];
    const float* c2_bh   = (const float*)d_in[23];

    // ws layout, ~289 MB of the 512 MiB workspace (fill evidence: poison writes 5.369e8 B)
    char* ws = (char*)d_ws;
    float* points1 = (float*)(ws + 0);                // 528384 B
    float* coarse  = (float*)(ws + 528384);           // 524288 B
    float* W2_1    = (float*)(ws + 1052672);
    float* b2_1    = (float*)(ws + 1054720);
    float* W2_2    = (float*)(ws + 1054976);
    float* b2_2    = (float*)(ws + 1057024);
    u16*   wb1a    = (u16*)(ws + 1057280);            // 294912 B
    u16*   wb1b    = (u16*)(ws + 1352192);
    u16*   wb2a    = (u16*)(ws + 1647104);            // 131072 B
    u16*   wb2b    = (u16*)(ws + 1778176);
    u16*   wqT1    = (u16*)(ws + 1909248);            // 393216 B
    u16*   wqT2    = (u16*)(ws + 2302464);
    u16*   inT     = (u16*)(ws + 2695680);            // 8*16384*64 bf16 = 16777216 B
    u16*   feat    = (u16*)(ws + 19472896);           // 8*16384*256 bf16 = 67108864 B
    u16*   relu_a  = (u16*)(ws + 86581760);           // 67108864 B
    u16*   xbuf    = (u16*)(ws + 153690624);          // 66048*256 bf16 = 33816576 B
    u16*   qkv_all = (u16*)(ws + 187507200);          // 66048*768 bf16 = 101449728 B
    // end: 288956928 B

    float* out0 = (float*)d_out;
    float* out1 = out0 + 131072;
    float* out2 = out0 + 262144;

    // prep
    k_cvt_w1<<<576, 256, 0, stream>>>(f1_w1, wb1a);
    k_cvt_w1<<<576, 256, 0, stream>>>(f2_w1, wb1b);
    k_cvt_w2<<<256, 256, 0, stream>>>(f1_w2, wb2a);
    k_cvt_w2<<<256, 256, 0, stream>>>(f2_w2, wb2b);
    k_cvt_wqkv<<<768, 256, 0, stream>>>(c1_wqkv, wqT1);
    k_cvt_wqkv<<<768, 256, 0, stream>>>(c2_wqkv, wqT2);
    k_headfuse<<<2, 256, 0, stream>>>(c1_wo, c1_bo, c1_wh, c1_bh, W2_1, b2_1);
    k_headfuse<<<2, 256, 0, stream>>>(c2_wo, c2_bo, c2_wh, c2_bh, W2_2, b2_2);
    k_init<<<NINST, 256, 0, stream>>>(whp, ct_ind, ct_img, points1, out0);
    k_nhwc<<<1024, 256, 0, stream>>>(cnn, inT);

    // ---- stage 1 ----
    k_conv_mfma<<<dim3(128, 2, 8), 256, 0, stream>>>(inT, wb1a, f1_b1, relu_a);
    k_gemm_mfma<<<dim3(1024, 2), 256, 0, stream>>>(relu_a, wb2a, f1_b2, 254, feat,
                                                   131072, 256, 256, 0);
    k_norm<<<NINST, 256, 0, stream>>>(points1, xbuf, 129);
    k_sample<<<dim3(NINST, 65), 256, 0, stream>>>(feat, points1, ct_img, xbuf, 129);
    k_gemm_mfma<<<dim3(516, 6), 256, 0, stream>>>(xbuf, wqT1, c1_bqkv, 768, qkv_all,
                                                  66048, 768, 256, 0);
    k_attn_mfma<<<dim3(NINST, 8), 256, 0, stream>>>(qkv_all, xbuf, 129);
    k_head1<<<16512, 256, 0, stream>>>(xbuf, W2_1, b2_1, points1, coarse, out1);

    // ---- stage 2 ----
    k_conv_mfma<<<dim3(128, 2, 8), 256, 0, stream>>>(inT, wb1b, f2_b1, relu_a);
    k_gemm_mfma<<<dim3(1024, 2), 256, 0, stream>>>(relu_a, wb2b, f2_b2, 254, feat,
                                                   131072, 256, 256, 0);
    k_norm<<<NINST, 256, 0, stream>>>(coarse, xbuf, 128);
    k_sample<<<dim3(NINST, 64), 256, 0, stream>>>(feat, coarse, ct_img, xbuf, 128);
    k_gemm_mfma<<<dim3(512, 6), 256, 0, stream>>>(xbuf, wqT2, c2_bqkv, 768, qkv_all,
                                                  65536, 768, 256, 0);
    k_attn_mfma<<<dim3(NINST, 8), 256, 0, stream>>>(qkv_all, xbuf, 128);
    k_head2<<<16384, 256, 0, stream>>>(xbuf, W2_2, b2_2, coarse, out2);
}